// Round 1
// 624.727 us; speedup vs baseline: 1.0813x; 1.0813x over previous
//
#include <hip/hip_runtime.h>
#include <hip/hip_bf16.h>

#define NN 50000
#define NE 500000
#define DD 128
#define HCC 128
#define TDD 32
#define MDD 64

typedef __hip_bfloat16 bf16;
typedef _Float16 f16;
typedef __attribute__((ext_vector_type(8))) _Float16 f16x8;
typedef __attribute__((ext_vector_type(2))) _Float16 f16x2;
typedef __attribute__((ext_vector_type(4))) float f32x4;

__device__ __forceinline__ float2 bf2x(unsigned u) {
    union { unsigned v; float f; } a, b;
    a.v = u << 16; b.v = u & 0xffff0000u;
    float2 r; r.x = a.f; r.y = b.f; return r;
}

// ---------------------------------------------------------------------------
// conv_x: x (f32) -> xh (f16)
// ---------------------------------------------------------------------------
__global__ __launch_bounds__(256) void conv_x_kernel(
    const float* __restrict__ x, f16* __restrict__ xh)
{
    int i = blockIdx.x * 256 + threadIdx.x;          // float4 index
    if (i >= NN * DD / 4) return;
    float4 v = ((const float4*)x)[i];
    f16 o[4] = { (f16)v.x, (f16)v.y, (f16)v.z, (f16)v.w };
    *(uint2*)&xh[(size_t)i * 4] = *(uint2*)o;
}

// ---------------------------------------------------------------------------
// conv_w: WTh[n][k] = Wcat[k][n] (f16, n in [0,512): q|k|v|skip), Weh = We f16,
// and zero cnt.
// ---------------------------------------------------------------------------
__global__ __launch_bounds__(256) void conv_w_kernel(
    const float* __restrict__ Wq, const float* __restrict__ Wk,
    const float* __restrict__ Wv, const float* __restrict__ Wsk,
    const float* __restrict__ We,
    f16* __restrict__ WTh, f16* __restrict__ Weh, int* __restrict__ cnt)
{
    int idx = blockIdx.x * 256 + threadIdx.x;
    if (idx < 512 * 128) {
        int n = idx >> 7, k = idx & 127;
        int mat = n >> 7, col = n & 127;
        const float* W = (mat == 0) ? Wq : (mat == 1) ? Wk : (mat == 2) ? Wv : Wsk;
        WTh[idx] = (f16)W[k * 128 + col];
    } else if (idx < 512 * 128 + 96 * 128) {
        int i = idx - 512 * 128;
        Weh[i] = (f16)We[i];
    } else if (idx < 512 * 128 + 96 * 128 + NN) {
        cnt[idx - (512 * 128 + 96 * 128)] = 0;
    }
}

// ---------------------------------------------------------------------------
// K1 (MFMA): out[g] = x @ W[g] + b[g].  grid = (782, 4).
// Block: 64 nodes x 128 cols. Wave: 16 nodes x 128 cols (8 col-tiles, K=128).
// g<3 -> f16 outputs (qh/kh/vh); g==3 -> f32 skip written to outp.
// LDS rows padded to 136 f16 (272 B): 2-way bank alias (free), 16B aligned.
// ---------------------------------------------------------------------------
__global__ __launch_bounds__(256) void node_proj_kernel(
    const f16* __restrict__ xh, const f16* __restrict__ WTh,
    const float* __restrict__ bq, const float* __restrict__ bk,
    const float* __restrict__ bv, const float* __restrict__ bsk,
    f16* __restrict__ qh, f16* __restrict__ kh, f16* __restrict__ vh,
    float* __restrict__ outp)
{
    __shared__ f16 xs[64 * 136];    // 17408 B
    __shared__ f16 ws[128 * 136];   // 34816 B

    const int node0 = blockIdx.x * 64;
    const int g = blockIdx.y;

    // stage x tile (64 x 128), 4 f16 per thread-iter
    for (int i = threadIdx.x; i < 64 * 32; i += 256) {
        int node = i >> 5, koff = (i & 31) * 4;
        int gn = node0 + node;
        uint2 val = {0u, 0u};
        if (gn < NN) val = *(const uint2*)&xh[(size_t)gn * DD + koff];
        *(uint2*)&xs[node * 136 + koff] = val;
    }
    // stage W^T tile (128 cols x 128 k) for matrix g
    const f16* wt = WTh + (size_t)g * 128 * 128;
    for (int i = threadIdx.x; i < 128 * 32; i += 256) {
        int n = i >> 5, koff = (i & 31) * 4;
        *(uint2*)&ws[n * 136 + koff] = *(const uint2*)&wt[n * 128 + koff];
    }
    __syncthreads();

    const int wave = threadIdx.x >> 6;
    const int lane = threadIdx.x & 63;
    const int m0 = wave * 16;
    const int lrow = lane & 15;          // A/B row-or-col index
    const int lk = (lane >> 4) * 8;      // k-chunk offset within 32

    f32x4 acc[8];
    #pragma unroll
    for (int t = 0; t < 8; t++) acc[t] = (f32x4){0.f, 0.f, 0.f, 0.f};

    #pragma unroll
    for (int kc = 0; kc < 4; kc++) {
        f16x8 a = *(const f16x8*)&xs[(m0 + lrow) * 136 + kc * 32 + lk];
        #pragma unroll
        for (int t = 0; t < 8; t++) {
            f16x8 b = *(const f16x8*)&ws[(t * 16 + lrow) * 136 + kc * 32 + lk];
            acc[t] = __builtin_amdgcn_mfma_f32_16x16x32_f16(a, b, acc[t], 0, 0, 0);
        }
    }

    const float* bias = (g == 0) ? bq : (g == 1) ? bk : (g == 2) ? bv : bsk;
    f16* outh = (g == 0) ? qh : (g == 1) ? kh : vh;

    #pragma unroll 1
    for (int t = 0; t < 8; t++) {
        int col = t * 16 + lrow;
        float bc = bias[col];
        #pragma unroll
        for (int r = 0; r < 4; r++) {
            int node = node0 + m0 + (lane >> 4) * 4 + r;
            if (node < NN) {
                float val = acc[t][r] + bc;
                if (g < 3) outh[(size_t)node * HCC + col] = (f16)val;
                else       outp[(size_t)node * HCC + col] = val;
            }
        }
    }
}

// ---------------------------------------------------------------------------
// K1b (MFMA): G[n][h*96+j] = sum_c qh[n][h*64+c] * Weh[j][h*64+c]  (bf16 out)
// Block: 64 nodes x 192 cols; wave: 16 nodes, 12 col-tiles (h = t/6), K=64.
// ---------------------------------------------------------------------------
__global__ __launch_bounds__(256) void g_kernel(
    const f16* __restrict__ qh, const f16* __restrict__ Weh,
    bf16* __restrict__ G)
{
    __shared__ f16 qs[64 * 136];   // 17408 B
    __shared__ f16 ws[96 * 136];   // 26112 B

    const int node0 = blockIdx.x * 64;
    for (int i = threadIdx.x; i < 64 * 32; i += 256) {
        int node = i >> 5, koff = (i & 31) * 4;
        int gn = node0 + node;
        uint2 val = {0u, 0u};
        if (gn < NN) val = *(const uint2*)&qh[(size_t)gn * DD + koff];
        *(uint2*)&qs[node * 136 + koff] = val;
    }
    for (int i = threadIdx.x; i < 96 * 32; i += 256) {
        int j = i >> 5, koff = (i & 31) * 4;
        *(uint2*)&ws[j * 136 + koff] = *(const uint2*)&Weh[j * 128 + koff];
    }
    __syncthreads();

    const int wave = threadIdx.x >> 6;
    const int lane = threadIdx.x & 63;
    const int m0 = wave * 16;
    const int lrow = lane & 15;
    const int lk = (lane >> 4) * 8;

    // preload the 4 A-fragments: (h, kc) in {0,1} x {0,1}
    f16x8 afr[4];
    #pragma unroll
    for (int hk = 0; hk < 4; hk++) {
        int h = hk >> 1, kc = hk & 1;
        afr[hk] = *(const f16x8*)&qs[(m0 + lrow) * 136 + h * 64 + kc * 32 + lk];
    }

    f32x4 acc[12];
    #pragma unroll
    for (int t = 0; t < 12; t++) acc[t] = (f32x4){0.f, 0.f, 0.f, 0.f};

    #pragma unroll
    for (int t = 0; t < 12; t++) {
        int h = (t < 6) ? 0 : 1;
        int jt = (t < 6) ? t : t - 6;
        #pragma unroll
        for (int kc = 0; kc < 2; kc++) {
            f16x8 b = *(const f16x8*)&ws[(jt * 16 + lrow) * 136 + h * 64 + kc * 32 + lk];
            acc[t] = __builtin_amdgcn_mfma_f32_16x16x32_f16(afr[h * 2 + kc], b, acc[t], 0, 0, 0);
        }
    }

    #pragma unroll 1
    for (int t = 0; t < 12; t++) {
        int h = (t < 6) ? 0 : 1;
        int jt = (t < 6) ? t : t - 6;
        int col = h * 96 + jt * 16 + lrow;
        #pragma unroll
        for (int r = 0; r < 4; r++) {
            int node = node0 + m0 + (lane >> 4) * 4 + r;
            if (node < NN) G[(size_t)node * 192 + col] = __float2bfloat16(acc[t][r]);
        }
    }
}

// --------------------------- sort pipeline ----------------------------------
__global__ __launch_bounds__(256) void hist_kernel(
    const int* __restrict__ ei, int* __restrict__ cnt)
{
    int gid = blockIdx.x * 256 + threadIdx.x;
    if (gid < NE) atomicAdd(&cnt[ei[NE + gid]], 1);
}

__global__ __launch_bounds__(256) void scan_a_kernel(
    const int* __restrict__ cnt, int* __restrict__ bsum)
{
    __shared__ int red[256];
    int gid = blockIdx.x * 256 + threadIdx.x;
    red[threadIdx.x] = (gid < NN) ? cnt[gid] : 0;
    __syncthreads();
    for (int off = 128; off > 0; off >>= 1) {
        if (threadIdx.x < off) red[threadIdx.x] += red[threadIdx.x + off];
        __syncthreads();
    }
    if (threadIdx.x == 0) bsum[blockIdx.x] = red[0];
}

__global__ __launch_bounds__(256) void scan_b_kernel(
    const int* __restrict__ bsum, int* __restrict__ boff, int* __restrict__ seg)
{
    __shared__ int s[256];
    int t = threadIdx.x;
    s[t] = (t < 196) ? bsum[t] : 0;
    __syncthreads();
    if (t == 0) {
        int run = 0;
        for (int b = 0; b < 196; b++) { int v = s[b]; s[b] = run; run += v; }
        seg[NN] = NE;
    }
    __syncthreads();
    if (t < 196) boff[t] = s[t];
}

__global__ __launch_bounds__(256) void scan_c_kernel(
    const int* __restrict__ cnt, const int* __restrict__ boff,
    int* __restrict__ seg, int* __restrict__ cur)
{
    __shared__ int s[256];
    int gid = blockIdx.x * 256 + threadIdx.x;
    int v = (gid < NN) ? cnt[gid] : 0;
    s[threadIdx.x] = v;
    __syncthreads();
    for (int off = 1; off < 256; off <<= 1) {
        int t = (threadIdx.x >= off) ? s[threadIdx.x - off] : 0;
        __syncthreads();
        s[threadIdx.x] += t;
        __syncthreads();
    }
    int excl = s[threadIdx.x] - v + boff[blockIdx.x];
    if (gid < NN) { seg[gid] = excl; cur[gid] = excl; }
}

__global__ __launch_bounds__(256) void scatter_kernel(
    const int* __restrict__ ei, const int* __restrict__ et,
    int* __restrict__ cur, int* __restrict__ perm,
    int* __restrict__ esrc, int* __restrict__ edst, float* __restrict__ etim)
{
    int gid = blockIdx.x * 256 + threadIdx.x;
    if (gid < NE) {
        int d = ei[NE + gid];
        int pos = atomicAdd(&cur[d], 1);
        perm[pos] = gid;
        esrc[pos] = ei[gid];
        edst[pos] = d;
        etim[pos] = (float)et[gid];
    }
}

// msg gather: 8 floats per thread (2x float4 load, 1x uint4 bf16 store).
// Old version was 1 float/thread: latency-bound at 15% HBM (112 us).
__global__ __launch_bounds__(256) void msg_gather_kernel(
    const float* __restrict__ msg, const int* __restrict__ perm,
    bf16* __restrict__ emsg)
{
    size_t idx = (size_t)blockIdx.x * 256 + threadIdx.x;   // 8-float slot
    if (idx >= (size_t)NE * 8) return;
    int i = (int)(idx >> 3);          // edge (8 threads per row)
    int c8 = (int)(idx & 7);          // which 8-float chunk of the 64
    const float4* row = (const float4*)(msg + ((size_t)perm[i] << 6));
    float4 v0 = row[c8 * 2];
    float4 v1 = row[c8 * 2 + 1];
    bf16 o[8] = { __float2bfloat16(v0.x), __float2bfloat16(v0.y),
                  __float2bfloat16(v0.z), __float2bfloat16(v0.w),
                  __float2bfloat16(v1.x), __float2bfloat16(v1.y),
                  __float2bfloat16(v1.z), __float2bfloat16(v1.w) };
    *(uint4*)&emsg[idx * 8] = *(uint4*)o;
}

// ---------------------------------------------------------------------------
// K2a: one THREAD per sorted edge (f16 q/k, dot2 HW path where available).
// ---------------------------------------------------------------------------
__global__ __launch_bounds__(256) void score_kernel(
    const int* __restrict__ esrc, const int* __restrict__ edst,
    const float* __restrict__ etim,
    const bf16* __restrict__ emsg,
    const float* __restrict__ Wt, const float* __restrict__ bt,
    const f16* __restrict__ qh, const f16* __restrict__ kh,
    const bf16* __restrict__ G, float2* __restrict__ exv)
{
    __shared__ float wt_s[TDD], bt_s[TDD];
    if (threadIdx.x < TDD) {
        wt_s[threadIdx.x] = Wt[threadIdx.x];
        bt_s[threadIdx.x] = bt[threadIdx.x];
    }
    __syncthreads();

    int i = blockIdx.x * 256 + threadIdx.x;
    if (i >= NE) return;

    int src = esrc[i], dst = edst[i];
    float t = etim[i];

    union U16 { uint4 u; f16x2 h[4]; };
    const uint4* qp = (const uint4*)(qh + (size_t)dst * DD);  // 8 f16 each
    const uint4* kp = (const uint4*)(kh + (size_t)src * DD);
    float qk0 = 0.f, qk1 = 0.f;
    #pragma unroll
    for (int c = 0; c < 8; c++) {
        U16 a, b; a.u = qp[c]; b.u = kp[c];
        #pragma unroll
        for (int j = 0; j < 4; j++) {
#if defined(__has_builtin) && __has_builtin(__builtin_amdgcn_fdot2)
            qk0 = __builtin_amdgcn_fdot2(a.h[j], b.h[j], qk0, false);
#else
            qk0 = fmaf((float)a.h[j][0], (float)b.h[j][0], qk0);
            qk0 = fmaf((float)a.h[j][1], (float)b.h[j][1], qk0);
#endif
        }
    }
    #pragma unroll
    for (int c = 8; c < 16; c++) {
        U16 a, b; a.u = qp[c]; b.u = kp[c];
        #pragma unroll
        for (int j = 0; j < 4; j++) {
#if defined(__has_builtin) && __has_builtin(__builtin_amdgcn_fdot2)
            qk1 = __builtin_amdgcn_fdot2(a.h[j], b.h[j], qk1, false);
#else
            qk1 = fmaf((float)a.h[j][0], (float)b.h[j][0], qk1);
            qk1 = fmaf((float)a.h[j][1], (float)b.h[j][1], qk1);
#endif
        }
    }

    const uint4* gp = (const uint4*)(G + (size_t)dst * 192);
    float u0 = 0.f, u1 = 0.f;

    // cos part: G[0..31] (h0) = gp[0..3], G[96..127] (h1) = gp[12..15]
    #pragma unroll
    for (int c = 0; c < 4; c++) {
        uint4 g0 = gp[c], g1 = gp[12 + c];
        float cj[8];
        #pragma unroll
        for (int j = 0; j < 8; j++)
            cj[j] = __cosf(fmaf(t, wt_s[8 * c + j], bt_s[8 * c + j]));
        float2 p;
        p = bf2x(g0.x); u0 = fmaf(cj[0], p.x, u0); u0 = fmaf(cj[1], p.y, u0);
        p = bf2x(g0.y); u0 = fmaf(cj[2], p.x, u0); u0 = fmaf(cj[3], p.y, u0);
        p = bf2x(g0.z); u0 = fmaf(cj[4], p.x, u0); u0 = fmaf(cj[5], p.y, u0);
        p = bf2x(g0.w); u0 = fmaf(cj[6], p.x, u0); u0 = fmaf(cj[7], p.y, u0);
        p = bf2x(g1.x); u1 = fmaf(cj[0], p.x, u1); u1 = fmaf(cj[1], p.y, u1);
        p = bf2x(g1.y); u1 = fmaf(cj[2], p.x, u1); u1 = fmaf(cj[3], p.y, u1);
        p = bf2x(g1.z); u1 = fmaf(cj[4], p.x, u1); u1 = fmaf(cj[5], p.y, u1);
        p = bf2x(g1.w); u1 = fmaf(cj[6], p.x, u1); u1 = fmaf(cj[7], p.y, u1);
    }

    // msg part
    const uint4* mp = (const uint4*)(emsg + ((size_t)i << 6));
    #pragma unroll
    for (int c = 0; c < 8; c++) {
        uint4 mu = mp[c];
        uint4 g0 = gp[4 + c], g1 = gp[16 + c];
        float2 m0 = bf2x(mu.x), m1 = bf2x(mu.y), m2 = bf2x(mu.z), m3 = bf2x(mu.w);
        float2 p;
        p = bf2x(g0.x); u0 = fmaf(m0.x, p.x, u0); u0 = fmaf(m0.y, p.y, u0);
        p = bf2x(g0.y); u0 = fmaf(m1.x, p.x, u0); u0 = fmaf(m1.y, p.y, u0);
        p = bf2x(g0.z); u0 = fmaf(m2.x, p.x, u0); u0 = fmaf(m2.y, p.y, u0);
        p = bf2x(g0.w); u0 = fmaf(m3.x, p.x, u0); u0 = fmaf(m3.y, p.y, u0);
        p = bf2x(g1.x); u1 = fmaf(m0.x, p.x, u1); u1 = fmaf(m0.y, p.y, u1);
        p = bf2x(g1.y); u1 = fmaf(m1.x, p.x, u1); u1 = fmaf(m1.y, p.y, u1);
        p = bf2x(g1.z); u1 = fmaf(m2.x, p.x, u1); u1 = fmaf(m2.y, p.y, u1);
        p = bf2x(g1.w); u1 = fmaf(m3.x, p.x, u1); u1 = fmaf(m3.y, p.y, u1);
    }

    float2 ex;
    ex.x = __expf((qk0 + u0) * 0.125f);
    ex.y = __expf((qk1 + u1) * 0.125f);
    exv[i] = ex;
}

// ---------------------------------------------------------------------------
// K2b: wave per dst node, streaming edge loop x4, f16 v gathers.
// ---------------------------------------------------------------------------
__global__ __launch_bounds__(256) void agg_kernel(
    const int* __restrict__ esrc, const float* __restrict__ etim,
    const bf16* __restrict__ emsg,
    const float* __restrict__ Wt, const float* __restrict__ bt,
    const f16* __restrict__ vh, const float2* __restrict__ exv,
    const int* __restrict__ seg,
    float* __restrict__ Sv, float* __restrict__ dnv,
    float* __restrict__ outp)
{
    __shared__ float wt_s[TDD], bt_s[TDD];
    if (threadIdx.x < TDD) {
        wt_s[threadIdx.x] = Wt[threadIdx.x];
        bt_s[threadIdx.x] = bt[threadIdx.x];
    }
    __syncthreads();

    const int lane = threadIdx.x & 63;
    const int gw = blockIdx.x * 4 + (threadIdx.x >> 6);
    const int NW = gridDim.x * 4;
    const bool half0 = (lane < 32);
    const float wtv = wt_s[lane & 31];
    const float btv = bt_s[lane & 31];
    const int mcol = half0 ? (32 + lane) : (lane - 32);

    for (int n = gw; n < NN; n += NW) {
        const int s0 = seg[n], s1 = seg[n + 1];

        float2 acc; acc.x = 0.f; acc.y = 0.f;
        float accd = 0.f;
        float s00 = 0.f, s01 = 0.f, s10 = 0.f, s11 = 0.f;

        int i = s0;
        #pragma unroll 1
        for (; i + 4 <= s1; i += 4) {
            int srcu[4]; float2 exu[4]; float ttu[4]; float mgu[4]; f16x2 vvu[4];
            #pragma unroll
            for (int u = 0; u < 4; u++) {
                srcu[u] = esrc[i + u];
                exu[u]  = exv[i + u];
                ttu[u]  = etim[i + u];
                mgu[u]  = __bfloat162float(emsg[((size_t)(i + u) << 6) + mcol]);
            }
            #pragma unroll
            for (int u = 0; u < 4; u++)
                vvu[u] = *(const f16x2*)&vh[(size_t)srcu[u] * HCC + 2 * lane];
            #pragma unroll
            for (int u = 0; u < 4; u++) {
                float cs = __cosf(fmaf(ttu[u], wtv, btv));
                float r0 = half0 ? cs : mgu[u];
                float r1 = half0 ? mgu[u] : 0.f;
                float exh = half0 ? exu[u].x : exu[u].y;
                acc.x = fmaf(exh, (float)vvu[u][0], acc.x);
                acc.y = fmaf(exh, (float)vvu[u][1], acc.y);
                accd += exh;
                s00 = fmaf(exu[u].x, r0, s00); s01 = fmaf(exu[u].x, r1, s01);
                s10 = fmaf(exu[u].y, r0, s10); s11 = fmaf(exu[u].y, r1, s11);
            }
        }
        #pragma unroll 1
        for (; i < s1; i++) {
            int src = esrc[i];
            float2 ex = exv[i];
            float tt = etim[i];
            float mg = __bfloat162float(emsg[((size_t)i << 6) + mcol]);
            f16x2 v2 = *(const f16x2*)&vh[(size_t)src * HCC + 2 * lane];
            float cs = __cosf(fmaf(tt, wtv, btv));
            float r0 = half0 ? cs : mg;
            float r1 = half0 ? mg : 0.f;
            float exh = half0 ? ex.x : ex.y;
            acc.x = fmaf(exh, (float)v2[0], acc.x);
            acc.y = fmaf(exh, (float)v2[1], acc.y);
            accd += exh;
            s00 = fmaf(ex.x, r0, s00); s01 = fmaf(ex.x, r1, s01);
            s10 = fmaf(ex.y, r0, s10); s11 = fmaf(ex.y, r1, s11);
        }

        float dn = accd + 1e-16f;
        size_t sb = (size_t)n * 192;
        Sv[sb + lane]      = s00;
        Sv[sb + 96 + lane] = s10;
        if (half0) {
            Sv[sb + 64 + lane]  = s01;
            Sv[sb + 160 + lane] = s11;
        }
        if ((lane & 31) == 0) dnv[n * 2 + (lane >> 5)] = accd;

        size_t nb = (size_t)n * HCC + 2 * lane;
        float2 sk = *(const float2*)&outp[nb];   // skip from node_proj
        float2 o;
        o.x = acc.x / dn + sk.x;
        o.y = acc.y / dn + sk.y;
        *(float2*)&outp[nb] = o;
    }
}

// ---------------------------------------------------------------------------
// K3: epilogue GEMM, out += (S @ We)/dn. 32 nodes/block, S transposed in LDS.
// ---------------------------------------------------------------------------
__global__ __launch_bounds__(256) void epi_kernel(
    const float* __restrict__ Sv, const float* __restrict__ dnv,
    const float* __restrict__ We, float* __restrict__ outp)
{
    __shared__ float st[192 * 36];  // 27.6 KB, st[c*36 + node]
    const int node0 = blockIdx.x * 32;
    for (int idx = threadIdx.x; idx < 32 * 192; idx += 256) {
        int n = idx / 192, c = idx - n * 192;
        int node = node0 + n;
        st[c * 36 + n] = (node < NN) ? Sv[(size_t)node * 192 + c] : 0.f;
    }
    __syncthreads();

    const int wave = threadIdx.x >> 6;
    const int lane = threadIdx.x & 63;
    const int nb = wave * 8;
    const int hoff = (lane < 32) ? 0 : 96;
    const float2* We2 = (const float2*)We;

    float a[8][2];
    #pragma unroll
    for (int n = 0; n < 8; n++) { a[n][0] = 0.f; a[n][1] = 0.f; }

    #pragma unroll 8
    for (int j = 0; j < 96; j++) {
        float2 w = We2[j * 64 + lane];
        const float* sr = &st[(hoff + j) * 36 + nb];
        float sv[8];
        *(float4*)&sv[0] = *(const float4*)sr;
        *(float4*)&sv[4] = *(const float4*)(sr + 4);
        #pragma unroll
        for (int n = 0; n < 8; n++) {
            a[n][0] = fmaf(sv[n], w.x, a[n][0]);
            a[n][1] = fmaf(sv[n], w.y, a[n][1]);
        }
    }

    #pragma unroll 1
    for (int n = 0; n < 8; n++) {
        int node = node0 + nb + n;
        if (node >= NN) break;
        float dn = dnv[node * 2 + (lane >> 5)] + 1e-16f;
        size_t b = (size_t)node * HCC + 2 * lane;
        float2 o = *(const float2*)&outp[b];
        o.x += a[n][0] / dn;
        o.y += a[n][1] / dn;
        *(float2*)&outp[b] = o;
    }
}

extern "C" void kernel_launch(void* const* d_in, const int* in_sizes, int n_in,
                              void* d_out, int out_size, void* d_ws, size_t ws_size,
                              hipStream_t stream) {
    const float* x   = (const float*)d_in[0];
    const int* ei    = (const int*)d_in[1];
    const int* et    = (const int*)d_in[2];
    const float* msg = (const float*)d_in[3];
    const float* Wt  = (const float*)d_in[4];
    const float* bt  = (const float*)d_in[5];
    const float* Wq  = (const float*)d_in[6];
    const float* bq  = (const float*)d_in[7];
    const float* Wk  = (const float*)d_in[8];
    const float* bk  = (const float*)d_in[9];
    const float* Wv  = (const float*)d_in[10];
    const float* bv  = (const float*)d_in[11];
    const float* We  = (const float*)d_in[12];
    const float* Wsk = (const float*)d_in[13];
    const float* bsk = (const float*)d_in[14];

    const size_t nf = (size_t)NN * HCC;
    f16* xh      = (f16*)d_ws;                    // NN*128
    f16* qh      = xh + nf;
    f16* kh      = qh + nf;
    f16* vh      = kh + nf;
    f16* WTh     = vh + nf;                       // 512*128
    f16* Weh     = WTh + 512 * 128;               // 96*128
    bf16* G      = (bf16*)(Weh + 96 * 128);       // NN*192
    bf16* emsg   = G + (size_t)NN * 192;          // NE*64
    float2* exv  = (float2*)(emsg + (size_t)NE * MDD);
    float* etim  = (float*)(exv + NE);
    float* Sv    = etim + NE;                     // NN*192
    float* dnv   = Sv + (size_t)NN * 192;         // NN*2
    int* cnt     = (int*)(dnv + (size_t)NN * 2);
    int* seg     = cnt + NN;                      // NN+1
    int* cur     = seg + NN + 1;
    int* perm    = cur + NN;
    int* esrc    = perm + NE;
    int* edst    = esrc + NE;
    int* bsum    = edst + NE;
    int* boff    = bsum + 256;
    size_t need  = (size_t)((char*)(boff + 256) - (char*)d_ws);
    if (ws_size < need) return;

    float* outp = (float*)d_out;

    conv_x_kernel<<<(NN * DD / 4 + 255) / 256, 256, 0, stream>>>(x, xh);
    conv_w_kernel<<<(512 * 128 + 96 * 128 + NN + 255) / 256, 256, 0, stream>>>(
        Wq, Wk, Wv, Wsk, We, WTh, Weh, cnt);
    dim3 npgrid((NN + 63) / 64, 4);
    node_proj_kernel<<<npgrid, 256, 0, stream>>>(
        xh, WTh, bq, bk, bv, bsk, qh, kh, vh, outp);
    g_kernel<<<(NN + 63) / 64, 256, 0, stream>>>(qh, Weh, G);
    hist_kernel<<<(NE + 255) / 256, 256, 0, stream>>>(ei, cnt);
    scan_a_kernel<<<196, 256, 0, stream>>>(cnt, bsum);
    scan_b_kernel<<<1, 256, 0, stream>>>(bsum, boff, seg);
    scan_c_kernel<<<196, 256, 0, stream>>>(cnt, boff, seg, cur);
    scatter_kernel<<<(NE + 255) / 256, 256, 0, stream>>>(
        ei, et, cur, perm, esrc, edst, etim);
    msg_gather_kernel<<<(int)(((size_t)NE * 8 + 255) / 256), 256, 0, stream>>>(
        msg, perm, emsg);
    score_kernel<<<(NE + 255) / 256, 256, 0, stream>>>(
        esrc, edst, etim, emsg, Wt, bt, qh, kh, G, exv);
    agg_kernel<<<3125, 256, 0, stream>>>(
        esrc, etim, emsg, Wt, bt, vh, exv, seg, Sv, dnv, outp);
    epi_kernel<<<(NN + 31) / 32, 256, 0, stream>>>(Sv, dnv, We, outp);
}

// Round 2
// 561.639 us; speedup vs baseline: 1.2028x; 1.1123x over previous
//
#include <hip/hip_runtime.h>
#include <hip/hip_bf16.h>

#define NN 50000
#define NE 500000
#define DD 128
#define HCC 128
#define TDD 32
#define MDD 64

typedef __hip_bfloat16 bf16;
typedef _Float16 f16;
typedef __attribute__((ext_vector_type(8))) _Float16 f16x8;
typedef __attribute__((ext_vector_type(2))) _Float16 f16x2;
typedef __attribute__((ext_vector_type(4))) float f32x4;

__device__ __forceinline__ float2 bf2x(unsigned u) {
    union { unsigned v; float f; } a, b;
    a.v = u << 16; b.v = u & 0xffff0000u;
    float2 r; r.x = a.f; r.y = b.f; return r;
}

// ---------------------------------------------------------------------------
// conv_x: x (f32) -> xh (f16)
// ---------------------------------------------------------------------------
__global__ __launch_bounds__(256) void conv_x_kernel(
    const float* __restrict__ x, f16* __restrict__ xh)
{
    int i = blockIdx.x * 256 + threadIdx.x;          // float4 index
    if (i >= NN * DD / 4) return;
    float4 v = ((const float4*)x)[i];
    f16 o[4] = { (f16)v.x, (f16)v.y, (f16)v.z, (f16)v.w };
    *(uint2*)&xh[(size_t)i * 4] = *(uint2*)o;
}

// ---------------------------------------------------------------------------
// conv_w: WTh[n][k] = Wcat[k][n] (f16, n in [0,512): q|k|v|skip), Weh = We f16,
// and zero cnt.
// ---------------------------------------------------------------------------
__global__ __launch_bounds__(256) void conv_w_kernel(
    const float* __restrict__ Wq, const float* __restrict__ Wk,
    const float* __restrict__ Wv, const float* __restrict__ Wsk,
    const float* __restrict__ We,
    f16* __restrict__ WTh, f16* __restrict__ Weh, int* __restrict__ cnt)
{
    int idx = blockIdx.x * 256 + threadIdx.x;
    if (idx < 512 * 128) {
        int n = idx >> 7, k = idx & 127;
        int mat = n >> 7, col = n & 127;
        const float* W = (mat == 0) ? Wq : (mat == 1) ? Wk : (mat == 2) ? Wv : Wsk;
        WTh[idx] = (f16)W[k * 128 + col];
    } else if (idx < 512 * 128 + 96 * 128) {
        int i = idx - 512 * 128;
        Weh[i] = (f16)We[i];
    } else if (idx < 512 * 128 + 96 * 128 + NN) {
        cnt[idx - (512 * 128 + 96 * 128)] = 0;
    }
}

// ---------------------------------------------------------------------------
// K1 (MFMA): out[g] = x @ W[g] + b[g].  grid = (782, 4).
// Block: 64 nodes x 128 cols. Wave: 16 nodes x 128 cols (8 col-tiles, K=128).
// g<3 -> f16 outputs (qh/kh/vh); g==3 -> f32 skip written to outp.
// LDS rows padded to 136 f16 (272 B): 2-way bank alias (free), 16B aligned.
// ---------------------------------------------------------------------------
__global__ __launch_bounds__(256) void node_proj_kernel(
    const f16* __restrict__ xh, const f16* __restrict__ WTh,
    const float* __restrict__ bq, const float* __restrict__ bk,
    const float* __restrict__ bv, const float* __restrict__ bsk,
    f16* __restrict__ qh, f16* __restrict__ kh, f16* __restrict__ vh,
    float* __restrict__ outp)
{
    __shared__ f16 xs[64 * 136];    // 17408 B
    __shared__ f16 ws[128 * 136];   // 34816 B

    const int node0 = blockIdx.x * 64;
    const int g = blockIdx.y;

    // stage x tile (64 x 128), 4 f16 per thread-iter
    for (int i = threadIdx.x; i < 64 * 32; i += 256) {
        int node = i >> 5, koff = (i & 31) * 4;
        int gn = node0 + node;
        uint2 val = {0u, 0u};
        if (gn < NN) val = *(const uint2*)&xh[(size_t)gn * DD + koff];
        *(uint2*)&xs[node * 136 + koff] = val;
    }
    // stage W^T tile (128 cols x 128 k) for matrix g
    const f16* wt = WTh + (size_t)g * 128 * 128;
    for (int i = threadIdx.x; i < 128 * 32; i += 256) {
        int n = i >> 5, koff = (i & 31) * 4;
        *(uint2*)&ws[n * 136 + koff] = *(const uint2*)&wt[n * 128 + koff];
    }
    __syncthreads();

    const int wave = threadIdx.x >> 6;
    const int lane = threadIdx.x & 63;
    const int m0 = wave * 16;
    const int lrow = lane & 15;          // A/B row-or-col index
    const int lk = (lane >> 4) * 8;      // k-chunk offset within 32

    f32x4 acc[8];
    #pragma unroll
    for (int t = 0; t < 8; t++) acc[t] = (f32x4){0.f, 0.f, 0.f, 0.f};

    #pragma unroll
    for (int kc = 0; kc < 4; kc++) {
        f16x8 a = *(const f16x8*)&xs[(m0 + lrow) * 136 + kc * 32 + lk];
        #pragma unroll
        for (int t = 0; t < 8; t++) {
            f16x8 b = *(const f16x8*)&ws[(t * 16 + lrow) * 136 + kc * 32 + lk];
            acc[t] = __builtin_amdgcn_mfma_f32_16x16x32_f16(a, b, acc[t], 0, 0, 0);
        }
    }

    const float* bias = (g == 0) ? bq : (g == 1) ? bk : (g == 2) ? bv : bsk;
    f16* outh = (g == 0) ? qh : (g == 1) ? kh : vh;

    #pragma unroll 1
    for (int t = 0; t < 8; t++) {
        int col = t * 16 + lrow;
        float bc = bias[col];
        #pragma unroll
        for (int r = 0; r < 4; r++) {
            int node = node0 + m0 + (lane >> 4) * 4 + r;
            if (node < NN) {
                float val = acc[t][r] + bc;
                if (g < 3) outh[(size_t)node * HCC + col] = (f16)val;
                else       outp[(size_t)node * HCC + col] = val;
            }
        }
    }
}

// ---------------------------------------------------------------------------
// K1b (MFMA): G[n][h*96+j] = sum_c qh[n][h*64+c] * Weh[j][h*64+c]  (bf16 out)
// Block: 64 nodes x 192 cols; wave: 16 nodes, 12 col-tiles (h = t/6), K=64.
// ---------------------------------------------------------------------------
__global__ __launch_bounds__(256) void g_kernel(
    const f16* __restrict__ qh, const f16* __restrict__ Weh,
    bf16* __restrict__ G)
{
    __shared__ f16 qs[64 * 136];   // 17408 B
    __shared__ f16 ws[96 * 136];   // 26112 B

    const int node0 = blockIdx.x * 64;
    for (int i = threadIdx.x; i < 64 * 32; i += 256) {
        int node = i >> 5, koff = (i & 31) * 4;
        int gn = node0 + node;
        uint2 val = {0u, 0u};
        if (gn < NN) val = *(const uint2*)&qh[(size_t)gn * DD + koff];
        *(uint2*)&qs[node * 136 + koff] = val;
    }
    for (int i = threadIdx.x; i < 96 * 32; i += 256) {
        int j = i >> 5, koff = (i & 31) * 4;
        *(uint2*)&ws[j * 136 + koff] = *(const uint2*)&Weh[j * 128 + koff];
    }
    __syncthreads();

    const int wave = threadIdx.x >> 6;
    const int lane = threadIdx.x & 63;
    const int m0 = wave * 16;
    const int lrow = lane & 15;
    const int lk = (lane >> 4) * 8;

    // preload the 4 A-fragments: (h, kc) in {0,1} x {0,1}
    f16x8 afr[4];
    #pragma unroll
    for (int hk = 0; hk < 4; hk++) {
        int h = hk >> 1, kc = hk & 1;
        afr[hk] = *(const f16x8*)&qs[(m0 + lrow) * 136 + h * 64 + kc * 32 + lk];
    }

    f32x4 acc[12];
    #pragma unroll
    for (int t = 0; t < 12; t++) acc[t] = (f32x4){0.f, 0.f, 0.f, 0.f};

    #pragma unroll
    for (int t = 0; t < 12; t++) {
        int h = (t < 6) ? 0 : 1;
        int jt = (t < 6) ? t : t - 6;
        #pragma unroll
        for (int kc = 0; kc < 2; kc++) {
            f16x8 b = *(const f16x8*)&ws[(jt * 16 + lrow) * 136 + h * 64 + kc * 32 + lk];
            acc[t] = __builtin_amdgcn_mfma_f32_16x16x32_f16(afr[h * 2 + kc], b, acc[t], 0, 0, 0);
        }
    }

    #pragma unroll 1
    for (int t = 0; t < 12; t++) {
        int h = (t < 6) ? 0 : 1;
        int jt = (t < 6) ? t : t - 6;
        int col = h * 96 + jt * 16 + lrow;
        #pragma unroll
        for (int r = 0; r < 4; r++) {
            int node = node0 + m0 + (lane >> 4) * 4 + r;
            if (node < NN) G[(size_t)node * 192 + col] = __float2bfloat16(acc[t][r]);
        }
    }
}

// --------------------------- sort pipeline ----------------------------------
__global__ __launch_bounds__(256) void hist_kernel(
    const int* __restrict__ ei, int* __restrict__ cnt)
{
    int gid = blockIdx.x * 256 + threadIdx.x;
    if (gid < NE) atomicAdd(&cnt[ei[NE + gid]], 1);
}

__global__ __launch_bounds__(256) void scan_a_kernel(
    const int* __restrict__ cnt, int* __restrict__ bsum)
{
    __shared__ int red[256];
    int gid = blockIdx.x * 256 + threadIdx.x;
    red[threadIdx.x] = (gid < NN) ? cnt[gid] : 0;
    __syncthreads();
    for (int off = 128; off > 0; off >>= 1) {
        if (threadIdx.x < off) red[threadIdx.x] += red[threadIdx.x + off];
        __syncthreads();
    }
    if (threadIdx.x == 0) bsum[blockIdx.x] = red[0];
}

__global__ __launch_bounds__(256) void scan_b_kernel(
    const int* __restrict__ bsum, int* __restrict__ boff, int* __restrict__ seg)
{
    __shared__ int s[256];
    int t = threadIdx.x;
    s[t] = (t < 196) ? bsum[t] : 0;
    __syncthreads();
    if (t == 0) {
        int run = 0;
        for (int b = 0; b < 196; b++) { int v = s[b]; s[b] = run; run += v; }
        seg[NN] = NE;
    }
    __syncthreads();
    if (t < 196) boff[t] = s[t];
}

__global__ __launch_bounds__(256) void scan_c_kernel(
    const int* __restrict__ cnt, const int* __restrict__ boff,
    int* __restrict__ seg, int* __restrict__ cur)
{
    __shared__ int s[256];
    int gid = blockIdx.x * 256 + threadIdx.x;
    int v = (gid < NN) ? cnt[gid] : 0;
    s[threadIdx.x] = v;
    __syncthreads();
    for (int off = 1; off < 256; off <<= 1) {
        int t = (threadIdx.x >= off) ? s[threadIdx.x - off] : 0;
        __syncthreads();
        s[threadIdx.x] += t;
        __syncthreads();
    }
    int excl = s[threadIdx.x] - v + boff[blockIdx.x];
    if (gid < NN) { seg[gid] = excl; cur[gid] = excl; }
}

__global__ __launch_bounds__(256) void scatter_kernel(
    const int* __restrict__ ei, const int* __restrict__ et,
    int* __restrict__ cur, int* __restrict__ perm,
    int* __restrict__ esrc, int* __restrict__ edst, float* __restrict__ etim)
{
    int gid = blockIdx.x * 256 + threadIdx.x;
    if (gid < NE) {
        int d = ei[NE + gid];
        int pos = atomicAdd(&cur[d], 1);
        perm[pos] = gid;
        esrc[pos] = ei[gid];
        edst[pos] = d;
        etim[pos] = (float)et[gid];
    }
}

// ---------------------------------------------------------------------------
// Fused edge kernel: 8 threads per sorted edge.
// Each 8-lane group: gathers the msg row (32 B/lane), stores emsg (bf16),
// computes its slice of q.k (16 dims), cos.G (4 dims), msg.G (8 dims),
// then shfl_xor-reduces over the group; lane 0 writes exv.
// Replaces msg_gather (full emsg write pass) + score (which RE-READ emsg:
// 64 MB saved) and spreads the random kh row over 8 lanes (8x less address
// divergence per load instruction).
// ---------------------------------------------------------------------------
__global__ __launch_bounds__(256) void edge_fused_kernel(
    const float* __restrict__ msg, const int* __restrict__ perm,
    const int* __restrict__ esrc, const int* __restrict__ edst,
    const float* __restrict__ etim,
    const float* __restrict__ Wt, const float* __restrict__ bt,
    const f16* __restrict__ qh, const f16* __restrict__ kh,
    const bf16* __restrict__ G,
    bf16* __restrict__ emsg, float2* __restrict__ exv)
{
    __shared__ float wt_s[TDD], bt_s[TDD];
    if (threadIdx.x < TDD) {
        wt_s[threadIdx.x] = Wt[threadIdx.x];
        bt_s[threadIdx.x] = bt[threadIdx.x];
    }
    __syncthreads();

    size_t idx = (size_t)blockIdx.x * 256 + threadIdx.x;
    if (idx >= (size_t)NE * 8) return;
    int i = (int)(idx >> 3);          // sorted edge
    int sub = (int)(idx & 7);         // lane within edge group

    int src = esrc[i], dst = edst[i];
    float t = etim[i];
    int pe = perm[i];

    // ---- msg gather (dims 8*sub .. 8*sub+7) + bf16 convert + store ----
    const float4* mrow = (const float4*)(msg + ((size_t)pe << 6));
    float4 v0 = mrow[sub * 2];
    float4 v1 = mrow[sub * 2 + 1];
    bf16 o[8] = { __float2bfloat16(v0.x), __float2bfloat16(v0.y),
                  __float2bfloat16(v0.z), __float2bfloat16(v0.w),
                  __float2bfloat16(v1.x), __float2bfloat16(v1.y),
                  __float2bfloat16(v1.z), __float2bfloat16(v1.w) };
    *(uint4*)&emsg[((size_t)i << 6) + sub * 8] = *(uint4*)o;

    // ---- q.k partial: head0 dims [8sub,8sub+8), head1 dims [64+8sub, ..) ----
    union U16 { uint4 u; f16x2 h[4]; };
    const f16* qrow = qh + (size_t)dst * DD;
    const f16* krow = kh + (size_t)src * DD;
    U16 q0, k0, q1, k1;
    q0.u = *(const uint4*)(qrow + 8 * sub);
    k0.u = *(const uint4*)(krow + 8 * sub);
    q1.u = *(const uint4*)(qrow + 64 + 8 * sub);
    k1.u = *(const uint4*)(krow + 64 + 8 * sub);
    float s0 = 0.f, s1 = 0.f;
    #pragma unroll
    for (int j = 0; j < 4; j++) {
#if defined(__has_builtin) && __has_builtin(__builtin_amdgcn_fdot2)
        s0 = __builtin_amdgcn_fdot2(q0.h[j], k0.h[j], s0, false);
        s1 = __builtin_amdgcn_fdot2(q1.h[j], k1.h[j], s1, false);
#else
        s0 = fmaf((float)q0.h[j][0], (float)k0.h[j][0], s0);
        s0 = fmaf((float)q0.h[j][1], (float)k0.h[j][1], s0);
        s1 = fmaf((float)q1.h[j][0], (float)k1.h[j][0], s1);
        s1 = fmaf((float)q1.h[j][1], (float)k1.h[j][1], s1);
#endif
    }

    const bf16* grow = G + (size_t)dst * 192;

    // ---- cos part: dims 4*sub .. 4*sub+3 of TD=32 ----
    uint2 gc0 = *(const uint2*)(grow + 4 * sub);        // h0 cols 4sub..+3
    uint2 gc1 = *(const uint2*)(grow + 96 + 4 * sub);   // h1
    float cj[4];
    #pragma unroll
    for (int j = 0; j < 4; j++)
        cj[j] = __cosf(fmaf(t, wt_s[4 * sub + j], bt_s[4 * sub + j]));
    {
        float2 p;
        p = bf2x(gc0.x); s0 = fmaf(cj[0], p.x, s0); s0 = fmaf(cj[1], p.y, s0);
        p = bf2x(gc0.y); s0 = fmaf(cj[2], p.x, s0); s0 = fmaf(cj[3], p.y, s0);
        p = bf2x(gc1.x); s1 = fmaf(cj[0], p.x, s1); s1 = fmaf(cj[1], p.y, s1);
        p = bf2x(gc1.y); s1 = fmaf(cj[2], p.x, s1); s1 = fmaf(cj[3], p.y, s1);
    }

    // ---- msg part: dims 8*sub .. 8*sub+7 of MD=64 ----
    uint4 gm0 = *(const uint4*)(grow + 32 + 8 * sub);    // h0 cols 32+8sub..
    uint4 gm1 = *(const uint4*)(grow + 128 + 8 * sub);   // h1
    {
        float2 p;
        p = bf2x(gm0.x); s0 = fmaf(v0.x, p.x, s0); s0 = fmaf(v0.y, p.y, s0);
        p = bf2x(gm0.y); s0 = fmaf(v0.z, p.x, s0); s0 = fmaf(v0.w, p.y, s0);
        p = bf2x(gm0.z); s0 = fmaf(v1.x, p.x, s0); s0 = fmaf(v1.y, p.y, s0);
        p = bf2x(gm0.w); s0 = fmaf(v1.z, p.x, s0); s0 = fmaf(v1.w, p.y, s0);
        p = bf2x(gm1.x); s1 = fmaf(v0.x, p.x, s1); s1 = fmaf(v0.y, p.y, s1);
        p = bf2x(gm1.y); s1 = fmaf(v0.z, p.x, s1); s1 = fmaf(v0.w, p.y, s1);
        p = bf2x(gm1.z); s1 = fmaf(v1.x, p.x, s1); s1 = fmaf(v1.y, p.y, s1);
        p = bf2x(gm1.w); s1 = fmaf(v1.z, p.x, s1); s1 = fmaf(v1.w, p.y, s1);
    }

    // ---- reduce over the 8-lane group ----
    #pragma unroll
    for (int off = 1; off < 8; off <<= 1) {
        s0 += __shfl_xor(s0, off);
        s1 += __shfl_xor(s1, off);
    }
    if (sub == 0) {
        float2 ex;
        ex.x = __expf(s0 * 0.125f);
        ex.y = __expf(s1 * 0.125f);
        exv[i] = ex;
    }
}

// ---------------------------------------------------------------------------
// K2b: wave per dst node, streaming edge loop x4, f16 v gathers.
// ---------------------------------------------------------------------------
__global__ __launch_bounds__(256) void agg_kernel(
    const int* __restrict__ esrc, const float* __restrict__ etim,
    const bf16* __restrict__ emsg,
    const float* __restrict__ Wt, const float* __restrict__ bt,
    const f16* __restrict__ vh, const float2* __restrict__ exv,
    const int* __restrict__ seg,
    float* __restrict__ Sv, float* __restrict__ dnv,
    float* __restrict__ outp)
{
    __shared__ float wt_s[TDD], bt_s[TDD];
    if (threadIdx.x < TDD) {
        wt_s[threadIdx.x] = Wt[threadIdx.x];
        bt_s[threadIdx.x] = bt[threadIdx.x];
    }
    __syncthreads();

    const int lane = threadIdx.x & 63;
    const int gw = blockIdx.x * 4 + (threadIdx.x >> 6);
    const int NW = gridDim.x * 4;
    const bool half0 = (lane < 32);
    const float wtv = wt_s[lane & 31];
    const float btv = bt_s[lane & 31];
    const int mcol = half0 ? (32 + lane) : (lane - 32);

    for (int n = gw; n < NN; n += NW) {
        const int s0 = seg[n], s1 = seg[n + 1];

        float2 acc; acc.x = 0.f; acc.y = 0.f;
        float accd = 0.f;
        float s00 = 0.f, s01 = 0.f, s10 = 0.f, s11 = 0.f;

        int i = s0;
        #pragma unroll 1
        for (; i + 4 <= s1; i += 4) {
            int srcu[4]; float2 exu[4]; float ttu[4]; float mgu[4]; f16x2 vvu[4];
            #pragma unroll
            for (int u = 0; u < 4; u++) {
                srcu[u] = esrc[i + u];
                exu[u]  = exv[i + u];
                ttu[u]  = etim[i + u];
                mgu[u]  = __bfloat162float(emsg[((size_t)(i + u) << 6) + mcol]);
            }
            #pragma unroll
            for (int u = 0; u < 4; u++)
                vvu[u] = *(const f16x2*)&vh[(size_t)srcu[u] * HCC + 2 * lane];
            #pragma unroll
            for (int u = 0; u < 4; u++) {
                float cs = __cosf(fmaf(ttu[u], wtv, btv));
                float r0 = half0 ? cs : mgu[u];
                float r1 = half0 ? mgu[u] : 0.f;
                float exh = half0 ? exu[u].x : exu[u].y;
                acc.x = fmaf(exh, (float)vvu[u][0], acc.x);
                acc.y = fmaf(exh, (float)vvu[u][1], acc.y);
                accd += exh;
                s00 = fmaf(exu[u].x, r0, s00); s01 = fmaf(exu[u].x, r1, s01);
                s10 = fmaf(exu[u].y, r0, s10); s11 = fmaf(exu[u].y, r1, s11);
            }
        }
        #pragma unroll 1
        for (; i < s1; i++) {
            int src = esrc[i];
            float2 ex = exv[i];
            float tt = etim[i];
            float mg = __bfloat162float(emsg[((size_t)i << 6) + mcol]);
            f16x2 v2 = *(const f16x2*)&vh[(size_t)src * HCC + 2 * lane];
            float cs = __cosf(fmaf(tt, wtv, btv));
            float r0 = half0 ? cs : mg;
            float r1 = half0 ? mg : 0.f;
            float exh = half0 ? ex.x : ex.y;
            acc.x = fmaf(exh, (float)v2[0], acc.x);
            acc.y = fmaf(exh, (float)v2[1], acc.y);
            accd += exh;
            s00 = fmaf(ex.x, r0, s00); s01 = fmaf(ex.x, r1, s01);
            s10 = fmaf(ex.y, r0, s10); s11 = fmaf(ex.y, r1, s11);
        }

        float dn = accd + 1e-16f;
        size_t sb = (size_t)n * 192;
        Sv[sb + lane]      = s00;
        Sv[sb + 96 + lane] = s10;
        if (half0) {
            Sv[sb + 64 + lane]  = s01;
            Sv[sb + 160 + lane] = s11;
        }
        if ((lane & 31) == 0) dnv[n * 2 + (lane >> 5)] = accd;

        size_t nb = (size_t)n * HCC + 2 * lane;
        float2 sk = *(const float2*)&outp[nb];   // skip from node_proj
        float2 o;
        o.x = acc.x / dn + sk.x;
        o.y = acc.y / dn + sk.y;
        *(float2*)&outp[nb] = o;
    }
}

// ---------------------------------------------------------------------------
// K3: epilogue GEMM, out += (S @ We)/dn. 32 nodes/block, S transposed in LDS.
// ---------------------------------------------------------------------------
__global__ __launch_bounds__(256) void epi_kernel(
    const float* __restrict__ Sv, const float* __restrict__ dnv,
    const float* __restrict__ We, float* __restrict__ outp)
{
    __shared__ float st[192 * 36];  // 27.6 KB, st[c*36 + node]
    const int node0 = blockIdx.x * 32;
    for (int idx = threadIdx.x; idx < 32 * 192; idx += 256) {
        int n = idx / 192, c = idx - n * 192;
        int node = node0 + n;
        st[c * 36 + n] = (node < NN) ? Sv[(size_t)node * 192 + c] : 0.f;
    }
    __syncthreads();

    const int wave = threadIdx.x >> 6;
    const int lane = threadIdx.x & 63;
    const int nb = wave * 8;
    const int hoff = (lane < 32) ? 0 : 96;
    const float2* We2 = (const float2*)We;

    float a[8][2];
    #pragma unroll
    for (int n = 0; n < 8; n++) { a[n][0] = 0.f; a[n][1] = 0.f; }

    #pragma unroll 8
    for (int j = 0; j < 96; j++) {
        float2 w = We2[j * 64 + lane];
        const float* sr = &st[(hoff + j) * 36 + nb];
        float sv[8];
        *(float4*)&sv[0] = *(const float4*)sr;
        *(float4*)&sv[4] = *(const float4*)(sr + 4);
        #pragma unroll
        for (int n = 0; n < 8; n++) {
            a[n][0] = fmaf(sv[n], w.x, a[n][0]);
            a[n][1] = fmaf(sv[n], w.y, a[n][1]);
        }
    }

    #pragma unroll 1
    for (int n = 0; n < 8; n++) {
        int node = node0 + nb + n;
        if (node >= NN) break;
        float dn = dnv[node * 2 + (lane >> 5)] + 1e-16f;
        size_t b = (size_t)node * HCC + 2 * lane;
        float2 o = *(const float2*)&outp[b];
        o.x += a[n][0] / dn;
        o.y += a[n][1] / dn;
        *(float2*)&outp[b] = o;
    }
}

extern "C" void kernel_launch(void* const* d_in, const int* in_sizes, int n_in,
                              void* d_out, int out_size, void* d_ws, size_t ws_size,
                              hipStream_t stream) {
    const float* x   = (const float*)d_in[0];
    const int* ei    = (const int*)d_in[1];
    const int* et    = (const int*)d_in[2];
    const float* msg = (const float*)d_in[3];
    const float* Wt  = (const float*)d_in[4];
    const float* bt  = (const float*)d_in[5];
    const float* Wq  = (const float*)d_in[6];
    const float* bq  = (const float*)d_in[7];
    const float* Wk  = (const float*)d_in[8];
    const float* bk  = (const float*)d_in[9];
    const float* Wv  = (const float*)d_in[10];
    const float* bv  = (const float*)d_in[11];
    const float* We  = (const float*)d_in[12];
    const float* Wsk = (const float*)d_in[13];
    const float* bsk = (const float*)d_in[14];

    const size_t nf = (size_t)NN * HCC;
    f16* xh      = (f16*)d_ws;                    // NN*128
    f16* qh      = xh + nf;
    f16* kh      = qh + nf;
    f16* vh      = kh + nf;
    f16* WTh     = vh + nf;                       // 512*128
    f16* Weh     = WTh + 512 * 128;               // 96*128
    bf16* G      = (bf16*)(Weh + 96 * 128);       // NN*192
    bf16* emsg   = G + (size_t)NN * 192;          // NE*64
    float2* exv  = (float2*)(emsg + (size_t)NE * MDD);
    float* etim  = (float*)(exv + NE);
    float* Sv    = etim + NE;                     // NN*192
    float* dnv   = Sv + (size_t)NN * 192;         // NN*2
    int* cnt     = (int*)(dnv + (size_t)NN * 2);
    int* seg     = cnt + NN;                      // NN+1
    int* cur     = seg + NN + 1;
    int* perm    = cur + NN;
    int* esrc    = perm + NE;
    int* edst    = esrc + NE;
    int* bsum    = edst + NE;
    int* boff    = bsum + 256;
    size_t need  = (size_t)((char*)(boff + 256) - (char*)d_ws);
    if (ws_size < need) return;

    float* outp = (float*)d_out;

    conv_x_kernel<<<(NN * DD / 4 + 255) / 256, 256, 0, stream>>>(x, xh);
    conv_w_kernel<<<(512 * 128 + 96 * 128 + NN + 255) / 256, 256, 0, stream>>>(
        Wq, Wk, Wv, Wsk, We, WTh, Weh, cnt);
    dim3 npgrid((NN + 63) / 64, 4);
    node_proj_kernel<<<npgrid, 256, 0, stream>>>(
        xh, WTh, bq, bk, bv, bsk, qh, kh, vh, outp);
    g_kernel<<<(NN + 63) / 64, 256, 0, stream>>>(qh, Weh, G);
    hist_kernel<<<(NE + 255) / 256, 256, 0, stream>>>(ei, cnt);
    scan_a_kernel<<<196, 256, 0, stream>>>(cnt, bsum);
    scan_b_kernel<<<1, 256, 0, stream>>>(bsum, boff, seg);
    scan_c_kernel<<<196, 256, 0, stream>>>(cnt, boff, seg, cur);
    scatter_kernel<<<(NE + 255) / 256, 256, 0, stream>>>(
        ei, et, cur, perm, esrc, edst, etim);
    edge_fused_kernel<<<(int)(((size_t)NE * 8 + 255) / 256), 256, 0, stream>>>(
        msg, perm, esrc, edst, etim, Wt, bt, qh, kh, G, emsg, exv);
    agg_kernel<<<3125, 256, 0, stream>>>(
        esrc, etim, emsg, Wt, bt, vh, exv, seg, Sv, dnv, outp);
    epi_kernel<<<(NN + 31) / 32, 256, 0, stream>>>(Sv, dnv, We, outp);
}

// Round 3
// 538.973 us; speedup vs baseline: 1.2534x; 1.0421x over previous
//
#include <hip/hip_runtime.h>
#include <hip/hip_bf16.h>

#define NN 50000
#define NE 500000
#define DD 128
#define HCC 128
#define TDD 32
#define MDD 64

typedef __hip_bfloat16 bf16;
typedef _Float16 f16;
typedef __attribute__((ext_vector_type(8))) _Float16 f16x8;
typedef __attribute__((ext_vector_type(2))) _Float16 f16x2;
typedef __attribute__((ext_vector_type(4))) float f32x4;

__device__ __forceinline__ float2 bf2x(unsigned u) {
    union { unsigned v; float f; } a, b;
    a.v = u << 16; b.v = u & 0xffff0000u;
    float2 r; r.x = a.f; r.y = b.f; return r;
}

// ---------------------------------------------------------------------------
// conv_w: WTh[n][k] = Wcat[k][n] (f16, n in [0,512): q|k|v|skip), Weh = We f16,
// and zero cnt.
// ---------------------------------------------------------------------------
__global__ __launch_bounds__(256) void conv_w_kernel(
    const float* __restrict__ Wq, const float* __restrict__ Wk,
    const float* __restrict__ Wv, const float* __restrict__ Wsk,
    const float* __restrict__ We,
    f16* __restrict__ WTh, f16* __restrict__ Weh, int* __restrict__ cnt)
{
    int idx = blockIdx.x * 256 + threadIdx.x;
    if (idx < 512 * 128) {
        int n = idx >> 7, k = idx & 127;
        int mat = n >> 7, col = n & 127;
        const float* W = (mat == 0) ? Wq : (mat == 1) ? Wk : (mat == 2) ? Wv : Wsk;
        WTh[idx] = (f16)W[k * 128 + col];
    } else if (idx < 512 * 128 + 96 * 128) {
        int i = idx - 512 * 128;
        Weh[i] = (f16)We[i];
    } else if (idx < 512 * 128 + 96 * 128 + NN) {
        cnt[idx - (512 * 128 + 96 * 128)] = 0;
    }
}

// ---------------------------------------------------------------------------
// K1 (MFMA): out[g] = x @ W[g] + b[g].  grid = (782, 4).
// Reads f32 x directly (conv_x pass eliminated; re-reads are L3 hits).
// Block: 64 nodes x 128 cols. Wave: 16 nodes x 128 cols (8 col-tiles, K=128).
// g<3 -> f16 outputs (qh/kh/vh); g==3 -> f32 skip written to outp.
// LDS rows padded to 136 f16 (272 B): 2-way bank alias (free), 16B aligned.
// ---------------------------------------------------------------------------
__global__ __launch_bounds__(256) void node_proj_kernel(
    const float* __restrict__ x, const f16* __restrict__ WTh,
    const float* __restrict__ bq, const float* __restrict__ bk,
    const float* __restrict__ bv, const float* __restrict__ bsk,
    f16* __restrict__ qh, f16* __restrict__ kh, f16* __restrict__ vh,
    float* __restrict__ outp)
{
    __shared__ f16 xs[64 * 136];    // 17408 B
    __shared__ f16 ws[128 * 136];   // 34816 B

    const int node0 = blockIdx.x * 64;
    const int g = blockIdx.y;

    // stage x tile (64 x 128), f32 -> f16 on the fly
    for (int i = threadIdx.x; i < 64 * 32; i += 256) {
        int node = i >> 5, koff = (i & 31) * 4;
        int gn = node0 + node;
        f16 o4[4] = { (f16)0.f, (f16)0.f, (f16)0.f, (f16)0.f };
        if (gn < NN) {
            float4 v = *(const float4*)&x[(size_t)gn * DD + koff];
            o4[0] = (f16)v.x; o4[1] = (f16)v.y; o4[2] = (f16)v.z; o4[3] = (f16)v.w;
        }
        *(uint2*)&xs[node * 136 + koff] = *(uint2*)o4;
    }
    // stage W^T tile (128 cols x 128 k) for matrix g
    const f16* wt = WTh + (size_t)g * 128 * 128;
    for (int i = threadIdx.x; i < 128 * 32; i += 256) {
        int n = i >> 5, koff = (i & 31) * 4;
        *(uint2*)&ws[n * 136 + koff] = *(const uint2*)&wt[n * 128 + koff];
    }
    __syncthreads();

    const int wave = threadIdx.x >> 6;
    const int lane = threadIdx.x & 63;
    const int m0 = wave * 16;
    const int lrow = lane & 15;          // A/B row-or-col index
    const int lk = (lane >> 4) * 8;      // k-chunk offset within 32

    f32x4 acc[8];
    #pragma unroll
    for (int t = 0; t < 8; t++) acc[t] = (f32x4){0.f, 0.f, 0.f, 0.f};

    #pragma unroll
    for (int kc = 0; kc < 4; kc++) {
        f16x8 a = *(const f16x8*)&xs[(m0 + lrow) * 136 + kc * 32 + lk];
        #pragma unroll
        for (int t = 0; t < 8; t++) {
            f16x8 b = *(const f16x8*)&ws[(t * 16 + lrow) * 136 + kc * 32 + lk];
            acc[t] = __builtin_amdgcn_mfma_f32_16x16x32_f16(a, b, acc[t], 0, 0, 0);
        }
    }

    const float* bias = (g == 0) ? bq : (g == 1) ? bk : (g == 2) ? bv : bsk;
    f16* outh = (g == 0) ? qh : (g == 1) ? kh : vh;

    #pragma unroll 1
    for (int t = 0; t < 8; t++) {
        int col = t * 16 + lrow;
        float bc = bias[col];
        #pragma unroll
        for (int r = 0; r < 4; r++) {
            int node = node0 + m0 + (lane >> 4) * 4 + r;
            if (node < NN) {
                float val = acc[t][r] + bc;
                if (g < 3) outh[(size_t)node * HCC + col] = (f16)val;
                else       outp[(size_t)node * HCC + col] = val;
            }
        }
    }
}

// ---------------------------------------------------------------------------
// K1b (MFMA): G[n][h*96+j] = sum_c qh[n][h*64+c] * Weh[j][h*64+c]  (bf16 out)
// Block: 64 nodes x 192 cols; wave: 16 nodes, 12 col-tiles (h = t/6), K=64.
// ---------------------------------------------------------------------------
__global__ __launch_bounds__(256) void g_kernel(
    const f16* __restrict__ qh, const f16* __restrict__ Weh,
    bf16* __restrict__ G)
{
    __shared__ f16 qs[64 * 136];   // 17408 B
    __shared__ f16 ws[96 * 136];   // 26112 B

    const int node0 = blockIdx.x * 64;
    for (int i = threadIdx.x; i < 64 * 32; i += 256) {
        int node = i >> 5, koff = (i & 31) * 4;
        int gn = node0 + node;
        uint2 val = {0u, 0u};
        if (gn < NN) val = *(const uint2*)&qh[(size_t)gn * DD + koff];
        *(uint2*)&qs[node * 136 + koff] = val;
    }
    for (int i = threadIdx.x; i < 96 * 32; i += 256) {
        int j = i >> 5, koff = (i & 31) * 4;
        *(uint2*)&ws[j * 136 + koff] = *(const uint2*)&Weh[j * 128 + koff];
    }
    __syncthreads();

    const int wave = threadIdx.x >> 6;
    const int lane = threadIdx.x & 63;
    const int m0 = wave * 16;
    const int lrow = lane & 15;
    const int lk = (lane >> 4) * 8;

    // preload the 4 A-fragments: (h, kc) in {0,1} x {0,1}
    f16x8 afr[4];
    #pragma unroll
    for (int hk = 0; hk < 4; hk++) {
        int h = hk >> 1, kc = hk & 1;
        afr[hk] = *(const f16x8*)&qs[(m0 + lrow) * 136 + h * 64 + kc * 32 + lk];
    }

    f32x4 acc[12];
    #pragma unroll
    for (int t = 0; t < 12; t++) acc[t] = (f32x4){0.f, 0.f, 0.f, 0.f};

    #pragma unroll
    for (int t = 0; t < 12; t++) {
        int h = (t < 6) ? 0 : 1;
        int jt = (t < 6) ? t : t - 6;
        #pragma unroll
        for (int kc = 0; kc < 2; kc++) {
            f16x8 b = *(const f16x8*)&ws[(jt * 16 + lrow) * 136 + h * 64 + kc * 32 + lk];
            acc[t] = __builtin_amdgcn_mfma_f32_16x16x32_f16(afr[h * 2 + kc], b, acc[t], 0, 0, 0);
        }
    }

    #pragma unroll 1
    for (int t = 0; t < 12; t++) {
        int h = (t < 6) ? 0 : 1;
        int jt = (t < 6) ? t : t - 6;
        int col = h * 96 + jt * 16 + lrow;
        #pragma unroll
        for (int r = 0; r < 4; r++) {
            int node = node0 + m0 + (lane >> 4) * 4 + r;
            if (node < NN) G[(size_t)node * 192 + col] = __float2bfloat16(acc[t][r]);
        }
    }
}

// --------------------------- sort pipeline ----------------------------------
__global__ __launch_bounds__(256) void hist_kernel(
    const int* __restrict__ ei, int* __restrict__ cnt)
{
    int gid = blockIdx.x * 256 + threadIdx.x;
    if (gid < NE) atomicAdd(&cnt[ei[NE + gid]], 1);
}

__global__ __launch_bounds__(256) void scan_a_kernel(
    const int* __restrict__ cnt, int* __restrict__ bsum)
{
    __shared__ int red[256];
    int gid = blockIdx.x * 256 + threadIdx.x;
    red[threadIdx.x] = (gid < NN) ? cnt[gid] : 0;
    __syncthreads();
    for (int off = 128; off > 0; off >>= 1) {
        if (threadIdx.x < off) red[threadIdx.x] += red[threadIdx.x + off];
        __syncthreads();
    }
    if (threadIdx.x == 0) bsum[blockIdx.x] = red[0];
}

__global__ __launch_bounds__(256) void scan_b_kernel(
    const int* __restrict__ bsum, int* __restrict__ boff, int* __restrict__ seg)
{
    __shared__ int s[256];
    int t = threadIdx.x;
    s[t] = (t < 196) ? bsum[t] : 0;
    __syncthreads();
    if (t == 0) {
        int run = 0;
        for (int b = 0; b < 196; b++) { int v = s[b]; s[b] = run; run += v; }
        seg[NN] = NE;
    }
    __syncthreads();
    if (t < 196) boff[t] = s[t];
}

__global__ __launch_bounds__(256) void scan_c_kernel(
    const int* __restrict__ cnt, const int* __restrict__ boff,
    int* __restrict__ seg, int* __restrict__ cur)
{
    __shared__ int s[256];
    int gid = blockIdx.x * 256 + threadIdx.x;
    int v = (gid < NN) ? cnt[gid] : 0;
    s[threadIdx.x] = v;
    __syncthreads();
    for (int off = 1; off < 256; off <<= 1) {
        int t = (threadIdx.x >= off) ? s[threadIdx.x - off] : 0;
        __syncthreads();
        s[threadIdx.x] += t;
        __syncthreads();
    }
    int excl = s[threadIdx.x] - v + boff[blockIdx.x];
    if (gid < NN) { seg[gid] = excl; cur[gid] = excl; }
}

// scatter: one packed 16-B store per edge {src, perm, time_bits, dst}
__global__ __launch_bounds__(256) void scatter_kernel(
    const int* __restrict__ ei, const int* __restrict__ et,
    int* __restrict__ cur, int4* __restrict__ epack)
{
    int gid = blockIdx.x * 256 + threadIdx.x;
    if (gid < NE) {
        int d = ei[NE + gid];
        int pos = atomicAdd(&cur[d], 1);
        int4 p;
        p.x = ei[gid];
        p.y = gid;
        p.z = __float_as_int((float)et[gid]);
        p.w = d;
        epack[pos] = p;
    }
}

// ---------------------------------------------------------------------------
// mega-agg: wave per dst node; per edge computes the score IN-WAVE and
// accumulates numerator + feature sums + denominator in one pass.
// Lane layout: lane l covers q/k/v dims {2l, 2l+1}; head0 = lanes 0..31,
// head1 = lanes 32..63 (dim 2l is automatically in head l>>5).
// c = lane&31: lane also covers cos col c and msg cols {2c, 2c+1} of its head.
// Score partial per lane = fdot2(q2,k2) + cos_c*Gc + m0*Gm0 + m1*Gm1;
// shfl_xor reduce over offsets 1..16 stays within each 32-lane half, so each
// half ends with ITS head's full score; no cross-half exchange needed.
// Eliminates emsg (64MB W + 64MB R), exv, and the separate edge kernel.
// Sv layout identical to before: per head [cos 0..31 | msg 0..63].
// ---------------------------------------------------------------------------
__global__ __launch_bounds__(256) void agg_kernel(
    const int4* __restrict__ epack, const float* __restrict__ msg,
    const float* __restrict__ Wt, const float* __restrict__ bt,
    const f16* __restrict__ qh, const f16* __restrict__ kh,
    const f16* __restrict__ vh, const bf16* __restrict__ G,
    const int* __restrict__ seg,
    float* __restrict__ Sv, float* __restrict__ dnv,
    float* __restrict__ outp)
{
    __shared__ float wt_s[TDD], bt_s[TDD];
    if (threadIdx.x < TDD) {
        wt_s[threadIdx.x] = Wt[threadIdx.x];
        bt_s[threadIdx.x] = bt[threadIdx.x];
    }
    __syncthreads();

    const int lane = threadIdx.x & 63;
    const int c = lane & 31;
    const int h = lane >> 5;
    const float wtv = wt_s[c];
    const float btv = bt_s[c];
    const int gw = blockIdx.x * 4 + (threadIdx.x >> 6);
    const int NW = gridDim.x * 4;

    for (int n = gw; n < NN; n += NW) {
        const int s0 = seg[n], s1 = seg[n + 1];

        // per-node preloads (dst == n)
        f16x2 q2 = *(const f16x2*)&qh[(size_t)n * DD + 2 * lane];
        const bf16* grow = G + (size_t)n * 192 + 96 * h;
        float Gc  = __bfloat162float(grow[c]);
        float Gm0 = __bfloat162float(grow[32 + 2 * c]);
        float Gm1 = __bfloat162float(grow[33 + 2 * c]);

        float2 acc; acc.x = 0.f; acc.y = 0.f;
        float accd = 0.f, sc = 0.f, sm0 = 0.f, sm1 = 0.f;

        int i = s0;
        #pragma unroll 1
        for (; i + 4 <= s1; i += 4) {
            int4 e[4]; f16x2 k2[4], v2[4]; float2 m[4];
            #pragma unroll
            for (int u = 0; u < 4; u++) e[u] = epack[i + u];
            #pragma unroll
            for (int u = 0; u < 4; u++) {
                int src = e[u].x;
                k2[u] = *(const f16x2*)&kh[(size_t)src * HCC + 2 * lane];
                v2[u] = *(const f16x2*)&vh[(size_t)src * HCC + 2 * lane];
                m[u]  = *(const float2*)&msg[((size_t)e[u].y << 6) + 2 * c];
            }
            #pragma unroll
            for (int u = 0; u < 4; u++) {
                float t = __int_as_float(e[u].z);
                float cs = __cosf(fmaf(t, wtv, btv));
                float p = fmaf(cs, Gc, fmaf(m[u].x, Gm0, m[u].y * Gm1));
#if defined(__has_builtin) && __has_builtin(__builtin_amdgcn_fdot2)
                p = __builtin_amdgcn_fdot2(q2, k2[u], p, false);
#else
                p = fmaf((float)q2[0], (float)k2[u][0], p);
                p = fmaf((float)q2[1], (float)k2[u][1], p);
#endif
                p += __shfl_xor(p, 1);
                p += __shfl_xor(p, 2);
                p += __shfl_xor(p, 4);
                p += __shfl_xor(p, 8);
                p += __shfl_xor(p, 16);
                float ex = __expf(p * 0.125f);
                acc.x = fmaf(ex, (float)v2[u][0], acc.x);
                acc.y = fmaf(ex, (float)v2[u][1], acc.y);
                accd += ex;
                sc  = fmaf(ex, cs, sc);
                sm0 = fmaf(ex, m[u].x, sm0);
                sm1 = fmaf(ex, m[u].y, sm1);
            }
        }
        #pragma unroll 1
        for (; i < s1; i++) {
            int4 e = epack[i];
            int src = e.x;
            f16x2 k2 = *(const f16x2*)&kh[(size_t)src * HCC + 2 * lane];
            f16x2 v2 = *(const f16x2*)&vh[(size_t)src * HCC + 2 * lane];
            float2 m = *(const float2*)&msg[((size_t)e.y << 6) + 2 * c];
            float t = __int_as_float(e.z);
            float cs = __cosf(fmaf(t, wtv, btv));
            float p = fmaf(cs, Gc, fmaf(m.x, Gm0, m.y * Gm1));
#if defined(__has_builtin) && __has_builtin(__builtin_amdgcn_fdot2)
            p = __builtin_amdgcn_fdot2(q2, k2, p, false);
#else
            p = fmaf((float)q2[0], (float)k2[0], p);
            p = fmaf((float)q2[1], (float)k2[1], p);
#endif
            p += __shfl_xor(p, 1);
            p += __shfl_xor(p, 2);
            p += __shfl_xor(p, 4);
            p += __shfl_xor(p, 8);
            p += __shfl_xor(p, 16);
            float ex = __expf(p * 0.125f);
            acc.x = fmaf(ex, (float)v2[0], acc.x);
            acc.y = fmaf(ex, (float)v2[1], acc.y);
            accd += ex;
            sc  = fmaf(ex, cs, sc);
            sm0 = fmaf(ex, m.x, sm0);
            sm1 = fmaf(ex, m.y, sm1);
        }

        float dn = accd + 1e-16f;
        size_t sb = (size_t)n * 192 + 96 * h;
        Sv[sb + c]          = sc;
        Sv[sb + 32 + 2 * c] = sm0;
        Sv[sb + 33 + 2 * c] = sm1;
        if (c == 0) dnv[n * 2 + h] = accd;

        size_t nb = (size_t)n * HCC + 2 * lane;
        float2 sk = *(const float2*)&outp[nb];   // skip from node_proj
        float2 o;
        o.x = acc.x / dn + sk.x;
        o.y = acc.y / dn + sk.y;
        *(float2*)&outp[nb] = o;
    }
}

// ---------------------------------------------------------------------------
// K3: epilogue GEMM, out += (S @ We)/dn. 32 nodes/block, S transposed in LDS.
// ---------------------------------------------------------------------------
__global__ __launch_bounds__(256) void epi_kernel(
    const float* __restrict__ Sv, const float* __restrict__ dnv,
    const float* __restrict__ We, float* __restrict__ outp)
{
    __shared__ float st[192 * 36];  // 27.6 KB, st[c*36 + node]
    const int node0 = blockIdx.x * 32;
    for (int idx = threadIdx.x; idx < 32 * 192; idx += 256) {
        int n = idx / 192, c = idx - n * 192;
        int node = node0 + n;
        st[c * 36 + n] = (node < NN) ? Sv[(size_t)node * 192 + c] : 0.f;
    }
    __syncthreads();

    const int wave = threadIdx.x >> 6;
    const int lane = threadIdx.x & 63;
    const int nb = wave * 8;
    const int hoff = (lane < 32) ? 0 : 96;
    const float2* We2 = (const float2*)We;

    float a[8][2];
    #pragma unroll
    for (int n = 0; n < 8; n++) { a[n][0] = 0.f; a[n][1] = 0.f; }

    #pragma unroll 8
    for (int j = 0; j < 96; j++) {
        float2 w = We2[j * 64 + lane];
        const float* sr = &st[(hoff + j) * 36 + nb];
        float sv[8];
        *(float4*)&sv[0] = *(const float4*)sr;
        *(float4*)&sv[4] = *(const float4*)(sr + 4);
        #pragma unroll
        for (int n = 0; n < 8; n++) {
            a[n][0] = fmaf(sv[n], w.x, a[n][0]);
            a[n][1] = fmaf(sv[n], w.y, a[n][1]);
        }
    }

    #pragma unroll 1
    for (int n = 0; n < 8; n++) {
        int node = node0 + nb + n;
        if (node >= NN) break;
        float dn = dnv[node * 2 + (lane >> 5)] + 1e-16f;
        size_t b = (size_t)node * HCC + 2 * lane;
        float2 o = *(const float2*)&outp[b];
        o.x += a[n][0] / dn;
        o.y += a[n][1] / dn;
        *(float2*)&outp[b] = o;
    }
}

extern "C" void kernel_launch(void* const* d_in, const int* in_sizes, int n_in,
                              void* d_out, int out_size, void* d_ws, size_t ws_size,
                              hipStream_t stream) {
    const float* x   = (const float*)d_in[0];
    const int* ei    = (const int*)d_in[1];
    const int* et    = (const int*)d_in[2];
    const float* msg = (const float*)d_in[3];
    const float* Wt  = (const float*)d_in[4];
    const float* bt  = (const float*)d_in[5];
    const float* Wq  = (const float*)d_in[6];
    const float* bq  = (const float*)d_in[7];
    const float* Wk  = (const float*)d_in[8];
    const float* bk  = (const float*)d_in[9];
    const float* Wv  = (const float*)d_in[10];
    const float* bv  = (const float*)d_in[11];
    const float* We  = (const float*)d_in[12];
    const float* Wsk = (const float*)d_in[13];
    const float* bsk = (const float*)d_in[14];

    const size_t nf = (size_t)NN * HCC;
    f16* qh      = (f16*)d_ws;                    // NN*128
    f16* kh      = qh + nf;
    f16* vh      = kh + nf;
    f16* WTh     = vh + nf;                       // 512*128
    f16* Weh     = WTh + 512 * 128;               // 96*128
    bf16* G      = (bf16*)(Weh + 96 * 128);       // NN*192
    float* Sv    = (float*)(G + (size_t)NN * 192);// NN*192 f32
    float* dnv   = Sv + (size_t)NN * 192;         // NN*2
    int4* epack  = (int4*)(dnv + (size_t)NN * 2); // NE int4 (16B-aligned: offsets even)
    int* cnt     = (int*)(epack + NE);
    int* seg     = cnt + NN;                      // NN+1
    int* cur     = seg + NN + 1;
    int* bsum    = cur + NN;
    int* boff    = bsum + 256;
    size_t need  = (size_t)((char*)(boff + 256) - (char*)d_ws);
    if (ws_size < need) return;

    float* outp = (float*)d_out;

    conv_w_kernel<<<(512 * 128 + 96 * 128 + NN + 255) / 256, 256, 0, stream>>>(
        Wq, Wk, Wv, Wsk, We, WTh, Weh, cnt);
    dim3 npgrid((NN + 63) / 64, 4);
    node_proj_kernel<<<npgrid, 256, 0, stream>>>(
        x, WTh, bq, bk, bv, bsk, qh, kh, vh, outp);
    g_kernel<<<(NN + 63) / 64, 256, 0, stream>>>(qh, Weh, G);
    hist_kernel<<<(NE + 255) / 256, 256, 0, stream>>>(ei, cnt);
    scan_a_kernel<<<196, 256, 0, stream>>>(cnt, bsum);
    scan_b_kernel<<<1, 256, 0, stream>>>(bsum, boff, seg);
    scan_c_kernel<<<196, 256, 0, stream>>>(cnt, boff, seg, cur);
    scatter_kernel<<<(NE + 255) / 256, 256, 0, stream>>>(ei, et, cur, epack);
    agg_kernel<<<3125, 256, 0, stream>>>(
        epack, msg, Wt, bt, qh, kh, vh, G, seg, Sv, dnv, outp);
    epi_kernel<<<(NN + 31) / 32, 256, 0, stream>>>(Sv, dnv, We, outp);
}

// Round 4
// 537.835 us; speedup vs baseline: 1.2561x; 1.0021x over previous
//
#include <hip/hip_runtime.h>
#include <hip/hip_bf16.h>

#define NN 50000
#define NE 500000
#define DD 128
#define HCC 128
#define TDD 32
#define MDD 64

typedef __hip_bfloat16 bf16;
typedef _Float16 f16;
typedef __attribute__((ext_vector_type(8))) _Float16 f16x8;
typedef __attribute__((ext_vector_type(2))) _Float16 f16x2;
typedef __attribute__((ext_vector_type(4))) float f32x4;

__device__ __forceinline__ float2 bf2x(unsigned u) {
    union { unsigned v; float f; } a, b;
    a.v = u << 16; b.v = u & 0xffff0000u;
    float2 r; r.x = a.f; r.y = b.f; return r;
}

#if defined(__has_builtin) && __has_builtin(__builtin_amdgcn_fdot2)
#define FDOT2(a, b, acc) __builtin_amdgcn_fdot2((a), (b), (acc), false)
#else
__device__ __forceinline__ float fdot2_sw(f16x2 a, f16x2 b, float acc) {
    acc = fmaf((float)a[0], (float)b[0], acc);
    return fmaf((float)a[1], (float)b[1], acc);
}
#define FDOT2(a, b, acc) fdot2_sw((a), (b), (acc))
#endif

// ---------------------------------------------------------------------------
// conv_w: WTh[n][k] = Wcat[k][n] (f16, n in [0,512): q|k|v|skip), Weh = We f16,
// and zero cnt.
// ---------------------------------------------------------------------------
__global__ __launch_bounds__(256) void conv_w_kernel(
    const float* __restrict__ Wq, const float* __restrict__ Wk,
    const float* __restrict__ Wv, const float* __restrict__ Wsk,
    const float* __restrict__ We,
    f16* __restrict__ WTh, f16* __restrict__ Weh, int* __restrict__ cnt)
{
    int idx = blockIdx.x * 256 + threadIdx.x;
    if (idx < 512 * 128) {
        int n = idx >> 7, k = idx & 127;
        int mat = n >> 7, col = n & 127;
        const float* W = (mat == 0) ? Wq : (mat == 1) ? Wk : (mat == 2) ? Wv : Wsk;
        WTh[idx] = (f16)W[k * 128 + col];
    } else if (idx < 512 * 128 + 96 * 128) {
        int i = idx - 512 * 128;
        Weh[i] = (f16)We[i];
    } else if (idx < 512 * 128 + 96 * 128 + NN) {
        cnt[idx - (512 * 128 + 96 * 128)] = 0;
    }
}

// ---------------------------------------------------------------------------
// K1 (MFMA): out[g] = x @ W[g] + b[g].  grid = (782, 4).
// g==0 -> qh; g==1/2 -> interleaved kvh row (blocks of 8: k[4j..4j+3] v[4j..4j+3],
// so agg reads one 16B f16x8 per lane covering its 4 k-dims AND 4 v-dims);
// g==3 -> f32 skip written to outp.
// ---------------------------------------------------------------------------
__global__ __launch_bounds__(256) void node_proj_kernel(
    const float* __restrict__ x, const f16* __restrict__ WTh,
    const float* __restrict__ bq, const float* __restrict__ bk,
    const float* __restrict__ bv, const float* __restrict__ bsk,
    f16* __restrict__ qh, f16* __restrict__ kvh,
    float* __restrict__ outp)
{
    __shared__ f16 xs[64 * 136];    // 17408 B
    __shared__ f16 ws[128 * 136];   // 34816 B

    const int node0 = blockIdx.x * 64;
    const int g = blockIdx.y;

    // stage x tile (64 x 128), f32 -> f16 on the fly
    for (int i = threadIdx.x; i < 64 * 32; i += 256) {
        int node = i >> 5, koff = (i & 31) * 4;
        int gn = node0 + node;
        f16 o4[4] = { (f16)0.f, (f16)0.f, (f16)0.f, (f16)0.f };
        if (gn < NN) {
            float4 v = *(const float4*)&x[(size_t)gn * DD + koff];
            o4[0] = (f16)v.x; o4[1] = (f16)v.y; o4[2] = (f16)v.z; o4[3] = (f16)v.w;
        }
        *(uint2*)&xs[node * 136 + koff] = *(uint2*)o4;
    }
    // stage W^T tile (128 cols x 128 k) for matrix g
    const f16* wt = WTh + (size_t)g * 128 * 128;
    for (int i = threadIdx.x; i < 128 * 32; i += 256) {
        int n = i >> 5, koff = (i & 31) * 4;
        *(uint2*)&ws[n * 136 + koff] = *(const uint2*)&wt[n * 128 + koff];
    }
    __syncthreads();

    const int wave = threadIdx.x >> 6;
    const int lane = threadIdx.x & 63;
    const int m0 = wave * 16;
    const int lrow = lane & 15;          // A/B row-or-col index
    const int lk = (lane >> 4) * 8;      // k-chunk offset within 32

    f32x4 acc[8];
    #pragma unroll
    for (int t = 0; t < 8; t++) acc[t] = (f32x4){0.f, 0.f, 0.f, 0.f};

    #pragma unroll
    for (int kc = 0; kc < 4; kc++) {
        f16x8 a = *(const f16x8*)&xs[(m0 + lrow) * 136 + kc * 32 + lk];
        #pragma unroll
        for (int t = 0; t < 8; t++) {
            f16x8 b = *(const f16x8*)&ws[(t * 16 + lrow) * 136 + kc * 32 + lk];
            acc[t] = __builtin_amdgcn_mfma_f32_16x16x32_f16(a, b, acc[t], 0, 0, 0);
        }
    }

    const float* bias = (g == 0) ? bq : (g == 1) ? bk : (g == 2) ? bv : bsk;

    #pragma unroll 1
    for (int t = 0; t < 8; t++) {
        int col = t * 16 + lrow;
        float bc = bias[col];
        #pragma unroll
        for (int r = 0; r < 4; r++) {
            int node = node0 + m0 + (lane >> 4) * 4 + r;
            if (node < NN) {
                float val = acc[t][r] + bc;
                if (g == 0)      qh[(size_t)node * DD + col] = (f16)val;
                else if (g == 3) outp[(size_t)node * HCC + col] = val;
                else {
                    int off = 8 * (col >> 2) + (col & 3) + ((g == 2) ? 4 : 0);
                    kvh[(size_t)node * 256 + off] = (f16)val;
                }
            }
        }
    }
}

// ---------------------------------------------------------------------------
// K1b (MFMA): G[n][h*96+j] = sum_c qh[n][h*64+c] * Weh[j][h*64+c]  (bf16 out)
// Block: 64 nodes x 192 cols; wave: 16 nodes, 12 col-tiles (h = t/6), K=64.
// ---------------------------------------------------------------------------
__global__ __launch_bounds__(256) void g_kernel(
    const f16* __restrict__ qh, const f16* __restrict__ Weh,
    bf16* __restrict__ G)
{
    __shared__ f16 qs[64 * 136];   // 17408 B
    __shared__ f16 ws[96 * 136];   // 26112 B

    const int node0 = blockIdx.x * 64;
    for (int i = threadIdx.x; i < 64 * 32; i += 256) {
        int node = i >> 5, koff = (i & 31) * 4;
        int gn = node0 + node;
        uint2 val = {0u, 0u};
        if (gn < NN) val = *(const uint2*)&qh[(size_t)gn * DD + koff];
        *(uint2*)&qs[node * 136 + koff] = val;
    }
    for (int i = threadIdx.x; i < 96 * 32; i += 256) {
        int j = i >> 5, koff = (i & 31) * 4;
        *(uint2*)&ws[j * 136 + koff] = *(const uint2*)&Weh[j * 128 + koff];
    }
    __syncthreads();

    const int wave = threadIdx.x >> 6;
    const int lane = threadIdx.x & 63;
    const int m0 = wave * 16;
    const int lrow = lane & 15;
    const int lk = (lane >> 4) * 8;

    // preload the 4 A-fragments: (h, kc) in {0,1} x {0,1}
    f16x8 afr[4];
    #pragma unroll
    for (int hk = 0; hk < 4; hk++) {
        int h = hk >> 1, kc = hk & 1;
        afr[hk] = *(const f16x8*)&qs[(m0 + lrow) * 136 + h * 64 + kc * 32 + lk];
    }

    f32x4 acc[12];
    #pragma unroll
    for (int t = 0; t < 12; t++) acc[t] = (f32x4){0.f, 0.f, 0.f, 0.f};

    #pragma unroll
    for (int t = 0; t < 12; t++) {
        int h = (t < 6) ? 0 : 1;
        int jt = (t < 6) ? t : t - 6;
        #pragma unroll
        for (int kc = 0; kc < 2; kc++) {
            f16x8 b = *(const f16x8*)&ws[(jt * 16 + lrow) * 136 + h * 64 + kc * 32 + lk];
            acc[t] = __builtin_amdgcn_mfma_f32_16x16x32_f16(afr[h * 2 + kc], b, acc[t], 0, 0, 0);
        }
    }

    #pragma unroll 1
    for (int t = 0; t < 12; t++) {
        int h = (t < 6) ? 0 : 1;
        int jt = (t < 6) ? t : t - 6;
        int col = h * 96 + jt * 16 + lrow;
        #pragma unroll
        for (int r = 0; r < 4; r++) {
            int node = node0 + m0 + (lane >> 4) * 4 + r;
            if (node < NN) G[(size_t)node * 192 + col] = __float2bfloat16(acc[t][r]);
        }
    }
}

// --------------------------- sort pipeline ----------------------------------
__global__ __launch_bounds__(256) void hist_kernel(
    const int* __restrict__ ei, int* __restrict__ cnt)
{
    int gid = blockIdx.x * 256 + threadIdx.x;
    if (gid < NE) atomicAdd(&cnt[ei[NE + gid]], 1);
}

__global__ __launch_bounds__(256) void scan_a_kernel(
    const int* __restrict__ cnt, int* __restrict__ bsum)
{
    __shared__ int red[256];
    int gid = blockIdx.x * 256 + threadIdx.x;
    red[threadIdx.x] = (gid < NN) ? cnt[gid] : 0;
    __syncthreads();
    for (int off = 128; off > 0; off >>= 1) {
        if (threadIdx.x < off) red[threadIdx.x] += red[threadIdx.x + off];
        __syncthreads();
    }
    if (threadIdx.x == 0) bsum[blockIdx.x] = red[0];
}

__global__ __launch_bounds__(256) void scan_b_kernel(
    const int* __restrict__ bsum, int* __restrict__ boff, int* __restrict__ seg)
{
    __shared__ int s[256];
    int t = threadIdx.x;
    s[t] = (t < 196) ? bsum[t] : 0;
    __syncthreads();
    if (t == 0) {
        int run = 0;
        for (int b = 0; b < 196; b++) { int v = s[b]; s[b] = run; run += v; }
        seg[NN] = NE;
    }
    __syncthreads();
    if (t < 196) boff[t] = s[t];
}

__global__ __launch_bounds__(256) void scan_c_kernel(
    const int* __restrict__ cnt, const int* __restrict__ boff,
    int* __restrict__ seg, int* __restrict__ cur)
{
    __shared__ int s[256];
    int gid = blockIdx.x * 256 + threadIdx.x;
    int v = (gid < NN) ? cnt[gid] : 0;
    s[threadIdx.x] = v;
    __syncthreads();
    for (int off = 1; off < 256; off <<= 1) {
        int t = (threadIdx.x >= off) ? s[threadIdx.x - off] : 0;
        __syncthreads();
        s[threadIdx.x] += t;
        __syncthreads();
    }
    int excl = s[threadIdx.x] - v + boff[blockIdx.x];
    if (gid < NN) { seg[gid] = excl; cur[gid] = excl; }
}

// scatter: one packed 16-B store per edge {src, perm, time_bits, dst}
__global__ __launch_bounds__(256) void scatter_kernel(
    const int* __restrict__ ei, const int* __restrict__ et,
    int* __restrict__ cur, int4* __restrict__ epack)
{
    int gid = blockIdx.x * 256 + threadIdx.x;
    if (gid < NE) {
        int d = ei[NE + gid];
        int pos = atomicAdd(&cur[d], 1);
        int4 p;
        p.x = ei[gid];
        p.y = gid;
        p.z = __float_as_int((float)et[gid]);
        p.w = d;
        epack[pos] = p;
    }
}

// ---------------------------------------------------------------------------
// mega-agg v2: wave per dst node, HALF-WAVE PER EDGE.
// Lane layout within a 32-lane half: lane covers q/k/v dims 4*l31..4*l31+3
// (lanes 0-15 = head0, 16-31 = head1); c = lane&15 also indexes cos cols
// {2c,2c+1} and msg cols {4c..4c+3} of its head.
// Per edge: one 16B kv load (interleaved kvh), one 16B msg load, score
// reduce = 4 shfl_xor steps within the 16-lane head group. Two edges are
// processed per wave iteration (one per half) -> 8 in flight at unroll 4.
// Cross-half combine (11 shfls) once per NODE at the end.
// ---------------------------------------------------------------------------
__global__ __launch_bounds__(256) void agg_kernel(
    const int4* __restrict__ epack, const float* __restrict__ msg,
    const float* __restrict__ Wt, const float* __restrict__ bt,
    const f16* __restrict__ qh, const f16* __restrict__ kvh,
    const bf16* __restrict__ G, const int* __restrict__ seg,
    float* __restrict__ Sv, float* __restrict__ dnv,
    float* __restrict__ outp)
{
    const int lane = threadIdx.x & 63;
    const int l31 = lane & 31;
    const int hl = (lane >> 4) & 1;   // head of this lane's 16-group
    const int c = lane & 15;
    const int halfid = lane >> 5;

    const float wt0 = Wt[2 * c], wt1 = Wt[2 * c + 1];
    const float bt0 = bt[2 * c], bt1 = bt[2 * c + 1];

    const int gw = blockIdx.x * 4 + (threadIdx.x >> 6);
    const int NW = gridDim.x * 4;

    union QU { uint2 u; f16x2 h[2]; };
    union KVU { uint4 u4; f16x2 h[4]; };

    for (int n = gw; n < NN; n += NW) {
        const int s0 = seg[n], s1 = seg[n + 1];

        QU q; q.u = *(const uint2*)&qh[(size_t)n * DD + 4 * l31];
        const bf16* grow = G + (size_t)n * 192 + 96 * hl;
        const float Gc0 = __bfloat162float(grow[2 * c]);
        const float Gc1 = __bfloat162float(grow[2 * c + 1]);
        const float Gm0 = __bfloat162float(grow[32 + 4 * c]);
        const float Gm1 = __bfloat162float(grow[33 + 4 * c]);
        const float Gm2 = __bfloat162float(grow[34 + 4 * c]);
        const float Gm3 = __bfloat162float(grow[35 + 4 * c]);

        f32x4 av = (f32x4){0.f, 0.f, 0.f, 0.f};
        f32x4 sm = (f32x4){0.f, 0.f, 0.f, 0.f};
        float accd = 0.f, sc0 = 0.f, sc1 = 0.f;

        auto edge_body = [&](int iu, bool pred) {
            int ic = pred ? iu : s0;        // clamp to a valid edge (s0<s1 here)
            int4 e = epack[ic];
            KVU kv;
            kv.u4 = *(const uint4*)&kvh[(size_t)e.x * 256 + 8 * l31];
            float4 m = *(const float4*)&msg[((size_t)e.y << 6) + 4 * c];
            float t = __int_as_float(e.z);
            float cs0 = __cosf(fmaf(t, wt0, bt0));
            float cs1 = __cosf(fmaf(t, wt1, bt1));
            float p = fmaf(cs0, Gc0, cs1 * Gc1);
            p = fmaf(m.x, Gm0, p); p = fmaf(m.y, Gm1, p);
            p = fmaf(m.z, Gm2, p); p = fmaf(m.w, Gm3, p);
            p = FDOT2(q.h[0], kv.h[0], p);
            p = FDOT2(q.h[1], kv.h[1], p);
            p += __shfl_xor(p, 1);
            p += __shfl_xor(p, 2);
            p += __shfl_xor(p, 4);
            p += __shfl_xor(p, 8);
            float ex = pred ? __expf(p * 0.125f) : 0.f;
            av.x = fmaf(ex, (float)kv.h[2][0], av.x);
            av.y = fmaf(ex, (float)kv.h[2][1], av.y);
            av.z = fmaf(ex, (float)kv.h[3][0], av.z);
            av.w = fmaf(ex, (float)kv.h[3][1], av.w);
            accd += ex;
            sc0 = fmaf(ex, cs0, sc0);
            sc1 = fmaf(ex, cs1, sc1);
            sm.x = fmaf(ex, m.x, sm.x);
            sm.y = fmaf(ex, m.y, sm.y);
            sm.z = fmaf(ex, m.z, sm.z);
            sm.w = fmaf(ex, m.w, sm.w);
        };

        int ib = s0;
        #pragma unroll 1
        for (; ib + 8 <= s1; ib += 8) {       // exact: 8 edges, no predication
            #pragma unroll
            for (int u = 0; u < 4; u++)
                edge_body(ib + 2 * u + halfid, true);
        }
        #pragma unroll 1
        for (; ib < s1; ib += 2) {            // pair tail, odd-half predicated
            int iu = ib + halfid;
            edge_body(iu, iu < s1);
        }

        // cross-half combine (halves held alternate edges of the same node)
        av.x += __shfl_xor(av.x, 32);
        av.y += __shfl_xor(av.y, 32);
        av.z += __shfl_xor(av.z, 32);
        av.w += __shfl_xor(av.w, 32);
        accd += __shfl_xor(accd, 32);
        sc0  += __shfl_xor(sc0, 32);
        sc1  += __shfl_xor(sc1, 32);
        sm.x += __shfl_xor(sm.x, 32);
        sm.y += __shfl_xor(sm.y, 32);
        sm.z += __shfl_xor(sm.z, 32);
        sm.w += __shfl_xor(sm.w, 32);

        if (lane < 32) {
            float dn = accd + 1e-16f;
            size_t sb = (size_t)n * 192 + 96 * hl;
            float2 scv; scv.x = sc0; scv.y = sc1;
            *(float2*)&Sv[sb + 2 * c] = scv;
            float4 smv; smv.x = sm.x; smv.y = sm.y; smv.z = sm.z; smv.w = sm.w;
            *(float4*)&Sv[sb + 32 + 4 * c] = smv;
            if (c == 0) dnv[2 * n + hl] = accd;   // lanes 0 and 16

            size_t nb = (size_t)n * HCC + 4 * l31;
            float4 sk = *(const float4*)&outp[nb];   // skip from node_proj
            float4 o;
            o.x = av.x / dn + sk.x;
            o.y = av.y / dn + sk.y;
            o.z = av.z / dn + sk.z;
            o.w = av.w / dn + sk.w;
            *(float4*)&outp[nb] = o;
        }
    }
}

// ---------------------------------------------------------------------------
// K3: epilogue GEMM, out += (S @ We)/dn. 32 nodes/block, S transposed in LDS.
// ---------------------------------------------------------------------------
__global__ __launch_bounds__(256) void epi_kernel(
    const float* __restrict__ Sv, const float* __restrict__ dnv,
    const float* __restrict__ We, float* __restrict__ outp)
{
    __shared__ float st[192 * 36];  // 27.6 KB, st[c*36 + node]
    const int node0 = blockIdx.x * 32;
    for (int idx = threadIdx.x; idx < 32 * 192; idx += 256) {
        int n = idx / 192, c = idx - n * 192;
        int node = node0 + n;
        st[c * 36 + n] = (node < NN) ? Sv[(size_t)node * 192 + c] : 0.f;
    }
    __syncthreads();

    const int wave = threadIdx.x >> 6;
    const int lane = threadIdx.x & 63;
    const int nb = wave * 8;
    const int hoff = (lane < 32) ? 0 : 96;
    const float2* We2 = (const float2*)We;

    float a[8][2];
    #pragma unroll
    for (int n = 0; n < 8; n++) { a[n][0] = 0.f; a[n][1] = 0.f; }

    #pragma unroll 8
    for (int j = 0; j < 96; j++) {
        float2 w = We2[j * 64 + lane];
        const float* sr = &st[(hoff + j) * 36 + nb];
        float sv[8];
        *(float4*)&sv[0] = *(const float4*)sr;
        *(float4*)&sv[4] = *(const float4*)(sr + 4);
        #pragma unroll
        for (int n = 0; n < 8; n++) {
            a[n][0] = fmaf(sv[n], w.x, a[n][0]);
            a[n][1] = fmaf(sv[n], w.y, a[n][1]);
        }
    }

    #pragma unroll 1
    for (int n = 0; n < 8; n++) {
        int node = node0 + nb + n;
        if (node >= NN) break;
        float dn = dnv[node * 2 + (lane >> 5)] + 1e-16f;
        size_t b = (size_t)node * HCC + 2 * lane;
        float2 o = *(const float2*)&outp[b];
        o.x += a[n][0] / dn;
        o.y += a[n][1] / dn;
        *(float2*)&outp[b] = o;
    }
}

extern "C" void kernel_launch(void* const* d_in, const int* in_sizes, int n_in,
                              void* d_out, int out_size, void* d_ws, size_t ws_size,
                              hipStream_t stream) {
    const float* x   = (const float*)d_in[0];
    const int* ei    = (const int*)d_in[1];
    const int* et    = (const int*)d_in[2];
    const float* msg = (const float*)d_in[3];
    const float* Wt  = (const float*)d_in[4];
    const float* bt  = (const float*)d_in[5];
    const float* Wq  = (const float*)d_in[6];
    const float* bq  = (const float*)d_in[7];
    const float* Wk  = (const float*)d_in[8];
    const float* bk  = (const float*)d_in[9];
    const float* Wv  = (const float*)d_in[10];
    const float* bv  = (const float*)d_in[11];
    const float* We  = (const float*)d_in[12];
    const float* Wsk = (const float*)d_in[13];
    const float* bsk = (const float*)d_in[14];

    const size_t nf = (size_t)NN * HCC;
    f16* qh      = (f16*)d_ws;                    // NN*128
    f16* kvh     = qh + nf;                       // NN*256 (k/v interleaved)
    f16* WTh     = kvh + 2 * nf;                  // 512*128
    f16* Weh     = WTh + 512 * 128;               // 96*128
    bf16* G      = (bf16*)(Weh + 96 * 128);       // NN*192
    float* Sv    = (float*)(G + (size_t)NN * 192);// NN*192 f32
    float* dnv   = Sv + (size_t)NN * 192;         // NN*2
    int4* epack  = (int4*)(dnv + (size_t)NN * 2); // NE int4
    int* cnt     = (int*)(epack + NE);
    int* seg     = cnt + NN;                      // NN+1
    int* cur     = seg + NN + 1;
    int* bsum    = cur + NN;
    int* boff    = bsum + 256;
    size_t need  = (size_t)((char*)(boff + 256) - (char*)d_ws);
    if (ws_size < need) return;

    float* outp = (float*)d_out;

    conv_w_kernel<<<(512 * 128 + 96 * 128 + NN + 255) / 256, 256, 0, stream>>>(
        Wq, Wk, Wv, Wsk, We, WTh, Weh, cnt);
    dim3 npgrid((NN + 63) / 64, 4);
    node_proj_kernel<<<npgrid, 256, 0, stream>>>(
        x, WTh, bq, bk, bv, bsk, qh, kvh, outp);
    g_kernel<<<(NN + 63) / 64, 256, 0, stream>>>(qh, Weh, G);
    hist_kernel<<<(NE + 255) / 256, 256, 0, stream>>>(ei, cnt);
    scan_a_kernel<<<196, 256, 0, stream>>>(cnt, bsum);
    scan_b_kernel<<<1, 256, 0, stream>>>(bsum, boff, seg);
    scan_c_kernel<<<196, 256, 0, stream>>>(cnt, boff, seg, cur);
    scatter_kernel<<<(NE + 255) / 256, 256, 0, stream>>>(ei, et, cur, epack);
    agg_kernel<<<3125, 256, 0, stream>>>(
        epack, msg, Wt, bt, qh, kvh, G, seg, Sv, dnv, outp);
    epi_kernel<<<(NN + 31) / 32, 256, 0, stream>>>(Sv, dnv, We, outp);
}